// Round 13
// baseline (1760.017 us; speedup 1.0000x reference)
//
#include <hip/hip_runtime.h>
#include <math.h>

#define NN 1024
#define HID 64
#define CIN 2
#define BB 8
#define TT 32
#define CG 66            // channels per support block, stored as [h0..h63,x0,x1]
#define NBC 528          // 8 * 66 channel rows in Abf
#define K2 384           // padded conv-channel count (330 -> 384)
#define GN_EPS 1e-5f
#define LDAP 72

typedef __attribute__((ext_vector_type(8))) short short8v;
typedef __attribute__((ext_vector_type(4))) float float4v;

// async global->LDS, 16B per lane. Dest is wave-uniform base + lane*16.
#define GLD16(gp, lp) __builtin_amdgcn_global_load_lds( \
    (const __attribute__((address_space(1))) void*)(gp), \
    (__attribute__((address_space(3))) void*)(lp), 16, 0, 0)

__device__ __forceinline__ unsigned short f2b(float v) {
    union { float f; unsigned int u; } a; a.f = v;
    unsigned int r = a.u + 0x7FFFu + ((a.u >> 16) & 1u);
    return (unsigned short)(r >> 16);
}
__device__ __forceinline__ float b2f(unsigned short b) {
    union { unsigned int u; float f; } a; a.u = ((unsigned int)b) << 16;
    return a.f;
}
__device__ __forceinline__ float sigmoidf_(float v) { return 1.f / (1.f + __expf(-v)); }

__device__ __forceinline__ float wave_reduce_sum(float v) {
    #pragma unroll
    for (int o = 32; o > 0; o >>= 1) v += __shfl_down(v, o, 64);
    return v;
}

// ---------------- one-time precompute ----------------

__global__ void rowsum_k(const float* __restrict__ adj, float* __restrict__ rs) {
    int i = blockIdx.x;
    float s = 0.f;
    for (int j = threadIdx.x; j < NN; j += 256) s += adj[(size_t)i * NN + j];
    s = wave_reduce_sum(s);
    __shared__ float sh[4];
    int wid = threadIdx.x >> 6, lid = threadIdx.x & 63;
    if (lid == 0) sh[wid] = s;
    __syncthreads();
    if (threadIdx.x == 0) rs[i] = sh[0] + sh[1] + sh[2] + sh[3];
}

// deterministic column-sum partials: cpart[chunk][j] = sum of rows chunk*128..+127
__global__ void colsum_k(const float* __restrict__ adj, float* __restrict__ cpart) {
    int j = (blockIdx.x & 3) * 256 + threadIdx.x;
    int r0 = (blockIdx.x >> 2) * 128;
    float s = 0.f;
    for (int i = 0; i < 128; i++) s += adj[(size_t)(r0 + i) * NN + j];
    cpart[(size_t)(blockIdx.x >> 2) * NN + j] = s;
}

// suppb[0] = fwd (bf16)
__global__ void fwdb_k(const float* __restrict__ adj, const float* __restrict__ rs,
                       unsigned short* __restrict__ sb) {
    int idx = blockIdx.x * 256 + threadIdx.x;
    int i = idx >> 10;
    sb[idx] = f2b(adj[idx] / (rs[i] + 1e-8f));
}

// suppb[1] = bwd (bf16): bwd[i][j] = adj[j][i]/(colsum[i]+1e-8)
__global__ void bwdb_k(const float* __restrict__ adj, const float* __restrict__ cpart,
                       unsigned short* __restrict__ sb) {
    __shared__ float tile[32][33];
    int i0 = blockIdx.y * 32, j0 = blockIdx.x * 32;
    int tx = threadIdx.x, ty = threadIdx.y;   // 32 x 8
    #pragma unroll
    for (int r = ty; r < 32; r += 8)
        tile[r][tx] = adj[(size_t)(j0 + r) * NN + i0 + tx];
    __syncthreads();
    #pragma unroll
    for (int r = ty; r < 32; r += 8) {
        int i = i0 + r;
        float cs = 0.f;
        #pragma unroll
        for (int c = 0; c < 8; c++) cs += cpart[(size_t)c * NN + i];
        sb[(size_t)i * NN + j0 + tx] = f2b(tile[tx][r] / (cs + 1e-8f));
    }
}

// suppb[2+z] = suppb[z] @ suppb[z]^T, bf16 MFMA NT. grid (8,16,2), 256 thr.
__global__ __launch_bounds__(256) void suppk_mfma(const unsigned short* __restrict__ sb,
                                                  unsigned short* __restrict__ outb) {
    int z = blockIdx.z;
    const unsigned short* A = sb + (size_t)z * NN * NN;
    unsigned short* D = outb + (size_t)z * NN * NN;
    __shared__ unsigned short lA[128 * LDAP];
    __shared__ unsigned short lB[64 * LDAP];
    int tid = threadIdx.x;
    int m0 = blockIdx.x * 128, n0 = blockIdx.y * 64;
    int lane = tid & 63, wave = tid >> 6;
    int wm = wave >> 1, wn = wave & 1;          // wave tile 64m x 32n
    float4v acc[4][2];
    #pragma unroll
    for (int i = 0; i < 4; i++)
        #pragma unroll
        for (int j = 0; j < 2; j++) acc[i][j] = (float4v){0.f, 0.f, 0.f, 0.f};
    int lrow = lane & 15, lk8 = (lane >> 4) * 8;
    for (int k0 = 0; k0 < NN; k0 += 64) {
        #pragma unroll
        for (int s = 0; s < 4; s++) {
            int slot = tid + s * 256;
            int r = slot >> 3, kg = slot & 7;
            *(short8v*)(lA + r * LDAP + kg * 8) =
                *(const short8v*)(A + (size_t)(m0 + r) * NN + k0 + kg * 8);
        }
        #pragma unroll
        for (int s = 0; s < 2; s++) {
            int slot = tid + s * 256;
            int r = slot >> 3, kg = slot & 7;
            *(short8v*)(lB + r * LDAP + kg * 8) =
                *(const short8v*)(A + (size_t)(n0 + r) * NN + k0 + kg * 8);
        }
        __syncthreads();
        #pragma unroll
        for (int kk = 0; kk < 2; kk++) {
            short8v af[4], bf[2];
            #pragma unroll
            for (int i = 0; i < 4; i++)
                af[i] = *(const short8v*)(lA + (wm * 64 + i * 16 + lrow) * LDAP + kk * 32 + lk8);
            #pragma unroll
            for (int j = 0; j < 2; j++)
                bf[j] = *(const short8v*)(lB + (wn * 32 + j * 16 + lrow) * LDAP + kk * 32 + lk8);
            #pragma unroll
            for (int i = 0; i < 4; i++)
                #pragma unroll
                for (int j = 0; j < 2; j++)
                    acc[i][j] = __builtin_amdgcn_mfma_f32_16x16x32_bf16(af[i], bf[j], acc[i][j], 0, 0, 0);
        }
        __syncthreads();
    }
    int col = lane & 15, q4 = (lane >> 4) * 4;
    #pragma unroll
    for (int i = 0; i < 4; i++)
        #pragma unroll
        for (int j = 0; j < 2; j++) {
            int n = n0 + wn * 32 + j * 16 + col;
            #pragma unroll
            for (int r = 0; r < 4; r++) {
                int mm = m0 + wm * 64 + i * 16 + q4 + r;
                D[(size_t)mm * NN + n] = f2b(acc[i][j][r]);
            }
        }
}

// W (permuted cols, zero-padded) -> bf16. rows 0..63 Wr, 64..127 Wu -> Wb; 128..191 Wc -> Wcb
__global__ void wconv_k(const float* __restrict__ Wr, const float* __restrict__ Wu,
                        const float* __restrict__ Wc, unsigned short* __restrict__ Wb,
                        unsigned short* __restrict__ Wcb) {
    int idx = blockIdx.x * 256 + threadIdx.x;   // 192*384
    int row = idx / K2, j = idx - row * K2;
    float v = 0.f;
    if (j < 330) {
        int q = j / CG, rr = j - q * CG;
        int chan = q * CG + (rr < HID ? rr + CIN : rr - HID);
        if (row < 64) v = Wr[row * 330 + chan];
        else if (row < 128) v = Wu[(row - 64) * 330 + chan];
        else v = Wc[(row - 128) * 330 + chan];
    }
    if (row < 128) Wb[row * K2 + j] = f2b(v);
    else Wcb[(row - 128) * K2 + j] = f2b(v);
}

__global__ void zeroz_k(unsigned short* __restrict__ z) {
    size_t i = ((size_t)blockIdx.x * 256 + threadIdx.x) * 8;
    *(short8v*)(z + i) = (short8v){0, 0, 0, 0, 0, 0, 0, 0};
}

// init: h, Z2g self, Abfg rows from h0; x(t=0) into Z2g/Z2c/Abfg/Abfc
__global__ void init_k(const float* __restrict__ x, const float* __restrict__ h0,
                       float* __restrict__ h, unsigned short* __restrict__ Z2g,
                       unsigned short* __restrict__ Z2c, unsigned short* __restrict__ Abfg,
                       unsigned short* __restrict__ Abfc) {
    int m = blockIdx.x * 256 + threadIdx.x;   // 8192
    int b = m >> 10, n = m & 1023;
    for (int c = 0; c < HID; c++) {
        float v = h0[(c << 10) + n];
        h[(size_t)m * HID + c] = v;
        unsigned short hv = f2b(v);
        Z2g[(size_t)m * K2 + c] = hv;
        Abfg[(((size_t)(b * CG + c)) << 10) | n] = hv;
    }
    for (int o = 0; o < CIN; o++) {
        float xv = x[((((size_t)(b * CIN + o)) << 10) + n) * TT];
        unsigned short xb = f2b(xv);
        Z2g[(size_t)m * K2 + HID + o] = xb;
        Z2c[(size_t)m * K2 + HID + o] = xb;
        Abfg[(((size_t)(b * CG + HID + o)) << 10) | n] = xb;
        Abfc[(((size_t)(b * CG + HID + o)) << 10) | n] = xb;
    }
}

// ---------------- per-step kernels ----------------
// 3-buffer depth-2 prefetch pipeline: counted vmcnt (never 0 in main loop),
// one raw s_barrier per K-tile. LDS content: LDS[row][sz] = G[row][sz ^ (row&7)]
// (16B chunks); read chunk cb of row lr at LDS[lr*64 + ((cb ^ (lr&7))<<3)].

// agg (operand-swapped): D[(s,n)][bc] = sum_v suppb[s*1024+n][v] * Abf[bc][v]
// M=4096, N=576 (guard<528), K=1024. BM=64 BN=64 BK=64. 576 blocks, XCD-swizzled.
__global__ __launch_bounds__(256) void agg2_k(const unsigned short* __restrict__ S,
                                              const unsigned short* __restrict__ Abf,
                                              unsigned short* __restrict__ Z2) {
    __shared__ __align__(16) unsigned short lA[3][64 * 64];
    __shared__ __align__(16) unsigned short lB[3][64 * 64];
    int tid = threadIdx.x;
    // bijective XCD swizzle: 576 = 8 XCDs x 72 tiles; each XCD gets 8 consecutive
    // m-panels x 9 c-tiles -> supp footprint 1MB + Abf 1.2MB fits per-XCD L2.
    int lin = blockIdx.y * 9 + blockIdx.x;
    int swz = (lin & 7) * 72 + (lin >> 3);
    int c0 = (swz % 9) * 64;
    int m0 = (swz / 9) * 64;
    int lane = tid & 63, wave = tid >> 6;
    int wm = wave >> 1, wn = wave & 1;          // wave tile 32m x 32c
    float4v acc[2][2];
    #pragma unroll
    for (int i = 0; i < 2; i++)
        #pragma unroll
        for (int j = 0; j < 2; j++) acc[i][j] = (float4v){0.f, 0.f, 0.f, 0.f};
    int lrow = lane & 15, hi = lane >> 4;

    auto stage = [&](unsigned short* bufA, unsigned short* bufB, int k0) {
        #pragma unroll
        for (int i = 0; i < 2; i++) {
            int cid = (i * 4 + wave) * 64 + lane;
            int r = cid >> 3, sz = cid & 7;
            GLD16(S + (size_t)(m0 + r) * NN + k0 + ((sz ^ (r & 7)) << 3),
                  bufA + (i * 4 + wave) * 512);
        }
        #pragma unroll
        for (int i = 0; i < 2; i++) {
            int cid = (i * 4 + wave) * 64 + lane;
            int r = cid >> 3, sz = cid & 7;
            GLD16(Abf + (((size_t)(c0 + r)) << 10) + k0 + ((sz ^ (r & 7)) << 3),
                  bufB + (i * 4 + wave) * 512);
        }
    };

    unsigned short *a0 = lA[0], *a1 = lA[1], *a2 = lA[2];
    unsigned short *b0 = lB[0], *b1 = lB[1], *b2 = lB[2];
    stage(a0, b0, 0);
    stage(a1, b1, 64);
    for (int kt = 0; kt < 16; kt++) {
        if (kt < 15) asm volatile("s_waitcnt vmcnt(4)" ::: "memory");
        else         asm volatile("s_waitcnt vmcnt(0)" ::: "memory");
        __builtin_amdgcn_s_barrier();
        asm volatile("" ::: "memory");
        if (kt < 14) stage(a2, b2, (kt + 2) * 64);
        #pragma unroll
        for (int kk = 0; kk < 2; kk++) {
            int cb = kk * 4 + hi;
            short8v af[2], bf[2];
            #pragma unroll
            for (int i = 0; i < 2; i++) {
                int lr = wm * 32 + i * 16 + lrow;
                af[i] = *(const short8v*)(a0 + lr * 64 + ((cb ^ (lr & 7)) << 3));
            }
            #pragma unroll
            for (int j = 0; j < 2; j++) {
                int lr = wn * 32 + j * 16 + lrow;
                bf[j] = *(const short8v*)(b0 + lr * 64 + ((cb ^ (lr & 7)) << 3));
            }
            #pragma unroll
            for (int i = 0; i < 2; i++)
                #pragma unroll
                for (int j = 0; j < 2; j++)
                    acc[i][j] = __builtin_amdgcn_mfma_f32_16x16x32_bf16(af[i], bf[j], acc[i][j], 0, 0, 0);
        }
        { unsigned short* t = a0; a0 = a1; a1 = a2; a2 = t; }
        { unsigned short* t = b0; b0 = b1; b1 = b2; b2 = t; }
    }
    int col = lane & 15, q4 = (lane >> 4) * 4;
    int s_idx = m0 >> 10;
    int nb0 = (m0 & 1023) + wm * 32;
    #pragma unroll
    for (int j = 0; j < 2; j++) {
        int bc = c0 + wn * 32 + j * 16 + col;
        if (bc < NBC) {
            int b = bc / CG;
            int rr = bc - b * CG;
            size_t zcol = (size_t)CG + s_idx * CG + rr;
            #pragma unroll
            for (int i = 0; i < 2; i++) {
                int nb = nb0 + i * 16 + q4;
                #pragma unroll
                for (int r = 0; r < 4; r++)
                    Z2[((size_t)((b << 10) | (nb + r))) * K2 + zcol] = f2b(acc[i][j][r]);
            }
        }
    }
}

// gates: D[m][oo] = sum_k Z2g[m][k] * W[oo][k]; by=0 -> r (writes rh), by=1 -> u
// M=8192, N=64, K=384. BM=32 (cand-style), grid (256,2) = 512 blocks. NT=6, P=3.
__global__ __launch_bounds__(256) void gates_k2(const unsigned short* __restrict__ Z2g,
                                                const unsigned short* __restrict__ Wb,
                                                const float* __restrict__ br,
                                                const float* __restrict__ bu,
                                                const float* __restrict__ h,
                                                float* __restrict__ u,
                                                unsigned short* __restrict__ Z2c,
                                                unsigned short* __restrict__ Abfc) {
    __shared__ __align__(16) unsigned short lA[3][32 * 64];
    __shared__ __align__(16) unsigned short lB[3][64 * 64];
    int tid = threadIdx.x;
    int m0 = blockIdx.x * 32;
    int isU = blockIdx.y;
    const unsigned short* W = Wb + (size_t)isU * 64 * K2;
    int lane = tid & 63, wave = tid >> 6;
    int wm = wave >> 1, wn = wave & 1;          // wave tile 16m x 32o
    float4v acc[2];
    acc[0] = (float4v){0.f, 0.f, 0.f, 0.f};
    acc[1] = (float4v){0.f, 0.f, 0.f, 0.f};
    int lrow = lane & 15, hi = lane >> 4;

    auto stage = [&](unsigned short* bufA, unsigned short* bufB, int k0) {
        {
            int cid = wave * 64 + lane;         // 256 chunks for 32-row A tile
            int r = cid >> 3, sz = cid & 7;
            GLD16(Z2g + (size_t)(m0 + r) * K2 + k0 + ((sz ^ (r & 7)) << 3),
                  bufA + wave * 512);
        }
        #pragma unroll
        for (int i = 0; i < 2; i++) {
            int cid = (i * 4 + wave) * 64 + lane;
            int r = cid >> 3, sz = cid & 7;
            GLD16(W + (size_t)r * K2 + k0 + ((sz ^ (r & 7)) << 3),
                  bufB + (i * 4 + wave) * 512);
        }
    };

    unsigned short *a0 = lA[0], *a1 = lA[1], *a2 = lA[2];
    unsigned short *b0 = lB[0], *b1 = lB[1], *b2 = lB[2];
    stage(a0, b0, 0);
    stage(a1, b1, 64);
    for (int kt = 0; kt < 6; kt++) {
        if (kt < 5) asm volatile("s_waitcnt vmcnt(3)" ::: "memory");
        else        asm volatile("s_waitcnt vmcnt(0)" ::: "memory");
        __builtin_amdgcn_s_barrier();
        asm volatile("" ::: "memory");
        if (kt < 4) stage(a2, b2, (kt + 2) * 64);
        #pragma unroll
        for (int kk = 0; kk < 2; kk++) {
            int cb = kk * 4 + hi;
            short8v af, bf[2];
            {
                int lr = wm * 16 + lrow;
                af = *(const short8v*)(a0 + lr * 64 + ((cb ^ (lr & 7)) << 3));
            }
            #pragma unroll
            for (int j = 0; j < 2; j++) {
                int lr = wn * 32 + j * 16 + lrow;
                bf[j] = *(const short8v*)(b0 + lr * 64 + ((cb ^ (lr & 7)) << 3));
            }
            #pragma unroll
            for (int j = 0; j < 2; j++)
                acc[j] = __builtin_amdgcn_mfma_f32_16x16x32_bf16(af, bf[j], acc[j], 0, 0, 0);
        }
        { unsigned short* t = a0; a0 = a1; a1 = a2; a2 = t; }
        { unsigned short* t = b0; b0 = b1; b1 = b2; b2 = t; }
    }
    int col = lane & 15, q4 = (lane >> 4) * 4;
    #pragma unroll
    for (int j = 0; j < 2; j++) {
        int oo = wn * 32 + j * 16 + col;
        float bias = isU ? bu[oo] : br[oo];
        #pragma unroll
        for (int r = 0; r < 4; r++) {
            int m = m0 + wm * 16 + q4 + r;
            float g = sigmoidf_(acc[j][r] + bias);
            if (isU) {
                u[(size_t)m * HID + oo] = g;
            } else {
                float rh = g * h[(size_t)m * HID + oo];
                unsigned short hv = f2b(rh);
                Z2c[(size_t)m * K2 + oo] = hv;
                int b = m >> 10, n = m & 1023;
                Abfc[(((size_t)(b * CG + oo)) << 10) | n] = hv;
            }
        }
    }
}

// fused cand + apply: cv = tanh(Wc·Z2c + bc); hraw = u*h + (1-u)*cv (kept in
// LDS); batch-local stats sync via relaxed-poll counter (one release per
// block; no acquire-spin -> no round-10 L2-invalidate storm); then the
// apply body verbatim (GN + h update + x_hat + next-step build).
// BM=32 -> grid (256); all blocks co-resident (36KB LDS) -> no deadlock.
__global__ __launch_bounds__(256) void candapply_k(unsigned short* Z2c,
                                                   const unsigned short* __restrict__ Wcb,
                                                   const float* __restrict__ bcv,
                                                   const float* __restrict__ u,
                                                   float* h,
                                                   const float* __restrict__ gamma,
                                                   const float* __restrict__ beta,
                                                   const float* __restrict__ Wo,
                                                   const float* __restrict__ bo,
                                                   const float* __restrict__ x,
                                                   unsigned short* __restrict__ Z2g,
                                                   unsigned short* __restrict__ Abfg,
                                                   unsigned short* __restrict__ Abfc,
                                                   unsigned short* __restrict__ hseq8,
                                                   float* __restrict__ iseq,
                                                   float* __restrict__ stats2,
                                                   unsigned* __restrict__ cnt, int t) {
    __shared__ __align__(16) unsigned short lA[3][32 * 64];
    __shared__ __align__(16) unsigned short lB[3][64 * 64];
    __shared__ float sred[8];
    int tid = threadIdx.x;
    int m0 = blockIdx.x * 32;
    int lane = tid & 63, wave = tid >> 6;
    int wm = wave >> 1, wn = wave & 1;          // wave tile 16m x 32o
    float4v acc[2];
    acc[0] = (float4v){0.f, 0.f, 0.f, 0.f};
    acc[1] = (float4v){0.f, 0.f, 0.f, 0.f};
    int lrow = lane & 15, hi = lane >> 4;

    auto stage = [&](unsigned short* bufA, unsigned short* bufB, int k0) {
        {
            int cid = wave * 64 + lane;
            int r = cid >> 3, sz = cid & 7;
            GLD16(Z2c + (size_t)(m0 + r) * K2 + k0 + ((sz ^ (r & 7)) << 3),
                  bufA + wave * 512);
        }
        #pragma unroll
        for (int i = 0; i < 2; i++) {
            int cid = (i * 4 + wave) * 64 + lane;
            int r = cid >> 3, sz = cid & 7;
            GLD16(Wcb + (size_t)r * K2 + k0 + ((sz ^ (r & 7)) << 3),
                  bufB + (i * 4 + wave) * 512);
        }
    };

    unsigned short *a0 = lA[0], *a1 = lA[1], *a2 = lA[2];
    unsigned short *b0 = lB[0], *b1 = lB[1], *b2 = lB[2];
    stage(a0, b0, 0);
    stage(a1, b1, 64);
    for (int kt = 0; kt < 6; kt++) {
        if (kt < 5) asm volatile("s_waitcnt vmcnt(3)" ::: "memory");
        else        asm volatile("s_waitcnt vmcnt(0)" ::: "memory");
        __builtin_amdgcn_s_barrier();
        asm volatile("" ::: "memory");
        if (kt < 4) stage(a2, b2, (kt + 2) * 64);
        #pragma unroll
        for (int kk = 0; kk < 2; kk++) {
            int cb = kk * 4 + hi;
            short8v af, bf[2];
            {
                int lr = wm * 16 + lrow;
                af = *(const short8v*)(a0 + lr * 64 + ((cb ^ (lr & 7)) << 3));
            }
            #pragma unroll
            for (int j = 0; j < 2; j++) {
                int lr = wn * 32 + j * 16 + lrow;
                bf[j] = *(const short8v*)(b0 + lr * 64 + ((cb ^ (lr & 7)) << 3));
            }
            #pragma unroll
            for (int j = 0; j < 2; j++)
                acc[j] = __builtin_amdgcn_mfma_f32_16x16x32_bf16(af, bf[j], acc[j], 0, 0, 0);
        }
        { unsigned short* t_ = a0; a0 = a1; a1 = a2; a2 = t_; }
        { unsigned short* t_ = b0; b0 = b1; b1 = b2; b2 = t_; }
    }
    __syncthreads();                            // protect lA reuse as hr stage
    float* lds_h = (float*)lA;                  // [32][65] f32, pad -> 2-way banks
    int col = lane & 15, q4 = (lane >> 4) * 4;
    float ls = 0.f, ls2 = 0.f;
    #pragma unroll
    for (int j = 0; j < 2; j++) {
        int oo = wn * 32 + j * 16 + col;
        float bias = bcv[oo];
        #pragma unroll
        for (int r = 0; r < 4; r++) {
            int mrel = wm * 16 + q4 + r;
            int m = m0 + mrel;
            float cv = tanhf(acc[j][r] + bias);
            float uv = u[(size_t)m * HID + oo];
            float hv = h[(size_t)m * HID + oo];
            float hr = uv * hv + (1.f - uv) * cv;
            lds_h[mrel * 65 + oo] = hr;
            ls += hr;
            ls2 = fmaf(hr, hr, ls2);
        }
    }
    ls = wave_reduce_sum(ls);
    ls2 = wave_reduce_sum(ls2);
    if (lane == 0) { sred[wave] = ls; sred[4 + wave] = ls2; }
    __syncthreads();
    int b = blockIdx.x >> 5, slot = blockIdx.x & 31;
    if (tid == 0) {
        float S = sred[0] + sred[1] + sred[2] + sred[3];
        float S2 = sred[4] + sred[5] + sred[6] + sred[7];
        float* dst = stats2 + (((size_t)t * BB + b) * 32 + slot) * 2;
        // agent-scope (uncached) stores: no local-L2 stale copy can form
        __hip_atomic_store(dst + 0, S, __ATOMIC_RELAXED, __HIP_MEMORY_SCOPE_AGENT);
        __hip_atomic_store(dst + 1, S2, __ATOMIC_RELAXED, __HIP_MEMORY_SCOPE_AGENT);
        __hip_atomic_fetch_add(&cnt[t * 8 + b], 1u, __ATOMIC_RELEASE, __HIP_MEMORY_SCOPE_AGENT);
        while (__hip_atomic_load(&cnt[t * 8 + b], __ATOMIC_RELAXED, __HIP_MEMORY_SCOPE_AGENT) < 32u)
            __builtin_amdgcn_s_sleep(8);
    }
    __syncthreads();
    asm volatile("" ::: "memory");

    // ---- apply part (verbatim apply_k2, hraw read from LDS) ----
    const float* st = stats2 + ((size_t)t * BB + b) * 64;
    float S = 0.f, S2 = 0.f;
    #pragma unroll
    for (int i = 0; i < 16; i++) {
        float4 p4 = *(const float4*)&st[i * 4];
        S += p4.x + p4.z;
        S2 += p4.y + p4.w;
    }
    float mean = S * (1.f / 65536.f);
    float rstd = rsqrtf(S2 * (1.f / 65536.f) - mean * mean + GN_EPS);
    bool more = (t < TT - 1);
    int mrel2 = tid >> 3, q = tid & 7;
    int m = m0 + mrel2;
    int n = m & 1023;
    int c0 = q * 8;
    float v[8];
    unsigned short hb[8];
    #pragma unroll
    for (int k = 0; k < 8; k++) {
        float raw = lds_h[mrel2 * 65 + c0 + k];
        v[k] = (raw - mean) * rstd * gamma[c0 + k] + beta[c0 + k];
    }
    float acc0 = 0.f, acc1 = 0.f;
    #pragma unroll
    for (int k = 0; k < 8; k++) {
        acc0 = fmaf(Wo[c0 + k], v[k], acc0);
        acc1 = fmaf(Wo[HID + c0 + k], v[k], acc1);
        hb[k] = f2b(v[k]);
    }
    short8v h8;
    #pragma unroll
    for (int k = 0; k < 8; k++) h8[k] = (short)hb[k];
    size_t hsbase = ((size_t)(t & 7) * 8192 + m) * HID + c0;
    *(short8v*)&hseq8[hsbase] = h8;
    if (more) {
        #pragma unroll
        for (int k = 0; k < 8; k += 4)
            *(float4*)&h[(size_t)m * HID + c0 + k] = make_float4(v[k], v[k + 1], v[k + 2], v[k + 3]);
        *(short8v*)&Z2g[(size_t)m * K2 + c0] = h8;
        #pragma unroll
        for (int k = 0; k < 8; k++)
            Abfg[(((size_t)(b * CG + c0 + k)) << 10) | n] = hb[k];
    }
    acc0 += __shfl_xor(acc0, 1, 64); acc0 += __shfl_xor(acc0, 2, 64); acc0 += __shfl_xor(acc0, 4, 64);
    acc1 += __shfl_xor(acc1, 1, 64); acc1 += __shfl_xor(acc1, 2, 64); acc1 += __shfl_xor(acc1, 4, 64);
    if (q == 0) {
        iseq[((size_t)t * 8192 + m) * 2 + 0] = acc0 + bo[0];
        iseq[((size_t)t * 8192 + m) * 2 + 1] = acc1 + bo[1];
        if (more) {
            #pragma unroll
            for (int o = 0; o < CIN; o++) {
                float xv = x[((((size_t)(b * CIN + o)) << 10) + n) * TT + t + 1];
                unsigned short xb = f2b(xv);
                Z2g[(size_t)m * K2 + HID + o] = xb;
                Z2c[(size_t)m * K2 + HID + o] = xb;
                Abfg[(((size_t)(b * CG + HID + o)) << 10) | n] = xb;
                Abfc[(((size_t)(b * CG + HID + o)) << 10) | n] = xb;
            }
        }
    }
}

// states chunk transpose: hseq8 [8][8192][64] bf16 -> out_states [b][c][n][t0..t0+7] f32
__global__ __launch_bounds__(256) void strans_k(const unsigned short* __restrict__ hseq8,
                                                float* __restrict__ outS, int t0) {
    __shared__ unsigned short lt[8 * 576];      // [tt][dn][c], dn stride 72
    int tid = threadIdx.x;
    int b = blockIdx.x >> 7;
    int n0 = (blockIdx.x & 127) * 8;
    #pragma unroll
    for (int s = 0; s < 2; s++) {
        int slot = tid + s * 256;               // 512 chunks of 8 shorts
        int tt = slot >> 6, dn = (slot >> 3) & 7, kc = slot & 7;
        short8v vv = *(const short8v*)(hseq8 + ((size_t)tt * 8192 + ((b << 10) | (n0 + dn))) * HID + kc * 8);
        *(short8v*)(lt + tt * 576 + dn * 72 + kc * 8) = vv;
    }
    __syncthreads();
    #pragma unroll
    for (int s = 0; s < 2; s++) {
        int rid = tid + s * 256;                // (c, dn)
        int c = rid >> 3, dn = rid & 7;
        float f[8];
        #pragma unroll
        for (int tt = 0; tt < 8; tt++) f[tt] = b2f(lt[tt * 576 + dn * 72 + c]);
        float* dst = outS + ((((size_t)(b * HID + c)) << 10) + n0 + dn) * TT + t0;
        *(float4*)&dst[0] = make_float4(f[0], f[1], f[2], f[3]);
        *(float4*)&dst[4] = make_float4(f[4], f[5], f[6], f[7]);
    }
}

// imputations transpose: iseq [32][8192][2] -> out [b][o][n][t]
__global__ void itrans_k(const float* __restrict__ iseq, float* __restrict__ out) {
    int gid = blockIdx.x * 256 + threadIdx.x;   // 16384
    int b = gid >> 11, o = (gid >> 10) & 1, n = gid & 1023;
    float f[TT];
    #pragma unroll
    for (int t = 0; t < TT; t++)
        f[t] = iseq[((size_t)t * 8192 + ((b << 10) | n)) * 2 + o];
    float* dst = out + ((((size_t)(b * CIN + o)) << 10) + n) * TT;
    #pragma unroll
    for (int k = 0; k < TT; k += 4)
        *(float4*)&dst[k] = make_float4(f[k], f[k + 1], f[k + 2], f[k + 3]);
}

// ---------------- launch ----------------

extern "C" void kernel_launch(void* const* d_in, const int* in_sizes, int n_in,
                              void* d_out, int out_size, void* d_ws, size_t ws_size,
                              hipStream_t stream) {
    const float* x     = (const float*)d_in[0];
    const float* adj   = (const float*)d_in[1];
    const float* h0    = (const float*)d_in[2];
    const float* Wr    = (const float*)d_in[3];
    const float* br    = (const float*)d_in[4];
    const float* Wu    = (const float*)d_in[5];
    const float* bu    = (const float*)d_in[6];
    const float* Wc    = (const float*)d_in[7];
    const float* bcv   = (const float*)d_in[8];
    const float* gamma = (const float*)d_in[9];
    const float* beta  = (const float*)d_in[10];
    const float* Wo    = (const float*)d_in[11];
    const float* bo    = (const float*)d_in[12];
    float* out = (float*)d_out;

    char* p = (char*)d_ws;
    unsigned short* suppb = (unsigned short*)p;  p += (size_t)4 * NN * NN * 2;          // 8 MB
    unsigned short* Abfg  = (unsigned short*)p;  p += (size_t)576 * NN * 2;
    unsigned short* Abfc  = (unsigned short*)p;  p += (size_t)576 * NN * 2;
    unsigned short* Z2g   = (unsigned short*)p;  p += (size_t)8192 * K2 * 2;
    unsigned short* Z2c   = (unsigned short*)p;  p += (size_t)8192 * K2 * 2;            // adjacent to Z2g
    unsigned short* Wb    = (unsigned short*)p;  p += (size_t)128 * K2 * 2;
    unsigned short* Wcb   = (unsigned short*)p;  p += (size_t)64 * K2 * 2;
    float* u     = (float*)p;  p += (size_t)8192 * HID * 4;
    float* h     = (float*)p;  p += (size_t)8192 * HID * 4;
    unsigned short* hseq8 = (unsigned short*)p;  p += (size_t)8 * 8192 * HID * 2;       // 8 MB
    float* iseq  = (float*)p;  p += (size_t)TT * 8192 * 2 * 4;
    float* rowsum = (float*)p; p += NN * 4;
    float* cpart  = (float*)p; p += (size_t)8 * NN * 4;
    float* stats2 = (float*)p; p += (size_t)TT * BB * 32 * 2 * 4;
    unsigned* cnt = (unsigned*)p; p += 1024;

    float* outS = out + (size_t)BB * CIN * NN * TT;

    hipMemsetAsync(cnt, 0, 1024, stream);

    rowsum_k<<<NN, 256, 0, stream>>>(adj, rowsum);
    colsum_k<<<32, 256, 0, stream>>>(adj, cpart);
    fwdb_k<<<(NN * NN) / 256, 256, 0, stream>>>(adj, rowsum, suppb);
    bwdb_k<<<dim3(32, 32), dim3(32, 8), 0, stream>>>(adj, cpart, suppb + (size_t)NN * NN);
    suppk_mfma<<<dim3(8, 16, 2), 256, 0, stream>>>(suppb, suppb + (size_t)2 * NN * NN);
    wconv_k<<<(192 * K2) / 256, 256, 0, stream>>>(Wr, Wu, Wc, Wb, Wcb);
    zeroz_k<<<(2 * 8192 * K2) / (8 * 256), 256, 0, stream>>>(Z2g);
    init_k<<<8192 / 256, 256, 0, stream>>>(x, h0, h, Z2g, Z2c, Abfg, Abfc);

    for (int t = 0; t < TT; t++) {
        agg2_k<<<dim3(9, 64), 256, 0, stream>>>(suppb, Abfg, Z2g);
        gates_k2<<<dim3(256, 2), 256, 0, stream>>>(Z2g, Wb, br, bu, h, u, Z2c, Abfc);
        agg2_k<<<dim3(9, 64), 256, 0, stream>>>(suppb, Abfc, Z2c);
        candapply_k<<<256, 256, 0, stream>>>(Z2c, Wcb, bcv, u, h, gamma, beta, Wo, bo,
                                             x, Z2g, Abfg, Abfc, hseq8, iseq,
                                             stats2, cnt, t);
        if ((t & 7) == 7)
            strans_k<<<1024, 256, 0, stream>>>(hseq8, outS, t - 7);
    }
    itrans_k<<<64, 256, 0, stream>>>(iseq, out);
}

// Round 14
// 1380.023 us; speedup vs baseline: 1.2754x; 1.2754x over previous
//
#include <hip/hip_runtime.h>
#include <math.h>

#define NN 1024
#define HID 64
#define CIN 2
#define BB 8
#define TT 32
#define CG 66            // channels per support block, stored as [h0..h63,x0,x1]
#define NBC 528          // 8 * 66 channel rows in Abf
#define K2 384           // padded conv-channel count (330 -> 384)
#define GN_EPS 1e-5f
#define LDAP 72

typedef __attribute__((ext_vector_type(8))) short short8v;
typedef __attribute__((ext_vector_type(4))) float float4v;

// async global->LDS, 16B per lane. Dest is wave-uniform base + lane*16.
#define GLD16(gp, lp) __builtin_amdgcn_global_load_lds( \
    (const __attribute__((address_space(1))) void*)(gp), \
    (__attribute__((address_space(3))) void*)(lp), 16, 0, 0)

__device__ __forceinline__ unsigned short f2b(float v) {
    union { float f; unsigned int u; } a; a.f = v;
    unsigned int r = a.u + 0x7FFFu + ((a.u >> 16) & 1u);
    return (unsigned short)(r >> 16);
}
__device__ __forceinline__ float b2f(unsigned short b) {
    union { unsigned int u; float f; } a; a.u = ((unsigned int)b) << 16;
    return a.f;
}
__device__ __forceinline__ float sigmoidf_(float v) { return 1.f / (1.f + __expf(-v)); }

__device__ __forceinline__ float wave_reduce_sum(float v) {
    #pragma unroll
    for (int o = 32; o > 0; o >>= 1) v += __shfl_down(v, o, 64);
    return v;
}

// ---------------- one-time precompute ----------------

__global__ void rowsum_k(const float* __restrict__ adj, float* __restrict__ rs) {
    int i = blockIdx.x;
    float s = 0.f;
    for (int j = threadIdx.x; j < NN; j += 256) s += adj[(size_t)i * NN + j];
    s = wave_reduce_sum(s);
    __shared__ float sh[4];
    int wid = threadIdx.x >> 6, lid = threadIdx.x & 63;
    if (lid == 0) sh[wid] = s;
    __syncthreads();
    if (threadIdx.x == 0) rs[i] = sh[0] + sh[1] + sh[2] + sh[3];
}

// deterministic column-sum partials: cpart[chunk][j] = sum of rows chunk*128..+127
__global__ void colsum_k(const float* __restrict__ adj, float* __restrict__ cpart) {
    int j = (blockIdx.x & 3) * 256 + threadIdx.x;
    int r0 = (blockIdx.x >> 2) * 128;
    float s = 0.f;
    for (int i = 0; i < 128; i++) s += adj[(size_t)(r0 + i) * NN + j];
    cpart[(size_t)(blockIdx.x >> 2) * NN + j] = s;
}

// suppb[0] = fwd (bf16)
__global__ void fwdb_k(const float* __restrict__ adj, const float* __restrict__ rs,
                       unsigned short* __restrict__ sb) {
    int idx = blockIdx.x * 256 + threadIdx.x;
    int i = idx >> 10;
    sb[idx] = f2b(adj[idx] / (rs[i] + 1e-8f));
}

// suppb[1] = bwd (bf16): bwd[i][j] = adj[j][i]/(colsum[i]+1e-8)
__global__ void bwdb_k(const float* __restrict__ adj, const float* __restrict__ cpart,
                       unsigned short* __restrict__ sb) {
    __shared__ float tile[32][33];
    int i0 = blockIdx.y * 32, j0 = blockIdx.x * 32;
    int tx = threadIdx.x, ty = threadIdx.y;   // 32 x 8
    #pragma unroll
    for (int r = ty; r < 32; r += 8)
        tile[r][tx] = adj[(size_t)(j0 + r) * NN + i0 + tx];
    __syncthreads();
    #pragma unroll
    for (int r = ty; r < 32; r += 8) {
        int i = i0 + r;
        float cs = 0.f;
        #pragma unroll
        for (int c = 0; c < 8; c++) cs += cpart[(size_t)c * NN + i];
        sb[(size_t)i * NN + j0 + tx] = f2b(tile[tx][r] / (cs + 1e-8f));
    }
}

// suppb[2+z] = suppb[z] @ suppb[z]^T, bf16 MFMA NT. grid (8,16,2), 256 thr.
__global__ __launch_bounds__(256) void suppk_mfma(const unsigned short* __restrict__ sb,
                                                  unsigned short* __restrict__ outb) {
    int z = blockIdx.z;
    const unsigned short* A = sb + (size_t)z * NN * NN;
    unsigned short* D = outb + (size_t)z * NN * NN;
    __shared__ unsigned short lA[128 * LDAP];
    __shared__ unsigned short lB[64 * LDAP];
    int tid = threadIdx.x;
    int m0 = blockIdx.x * 128, n0 = blockIdx.y * 64;
    int lane = tid & 63, wave = tid >> 6;
    int wm = wave >> 1, wn = wave & 1;          // wave tile 64m x 32n
    float4v acc[4][2];
    #pragma unroll
    for (int i = 0; i < 4; i++)
        #pragma unroll
        for (int j = 0; j < 2; j++) acc[i][j] = (float4v){0.f, 0.f, 0.f, 0.f};
    int lrow = lane & 15, lk8 = (lane >> 4) * 8;
    for (int k0 = 0; k0 < NN; k0 += 64) {
        #pragma unroll
        for (int s = 0; s < 4; s++) {
            int slot = tid + s * 256;
            int r = slot >> 3, kg = slot & 7;
            *(short8v*)(lA + r * LDAP + kg * 8) =
                *(const short8v*)(A + (size_t)(m0 + r) * NN + k0 + kg * 8);
        }
        #pragma unroll
        for (int s = 0; s < 2; s++) {
            int slot = tid + s * 256;
            int r = slot >> 3, kg = slot & 7;
            *(short8v*)(lB + r * LDAP + kg * 8) =
                *(const short8v*)(A + (size_t)(n0 + r) * NN + k0 + kg * 8);
        }
        __syncthreads();
        #pragma unroll
        for (int kk = 0; kk < 2; kk++) {
            short8v af[4], bf[2];
            #pragma unroll
            for (int i = 0; i < 4; i++)
                af[i] = *(const short8v*)(lA + (wm * 64 + i * 16 + lrow) * LDAP + kk * 32 + lk8);
            #pragma unroll
            for (int j = 0; j < 2; j++)
                bf[j] = *(const short8v*)(lB + (wn * 32 + j * 16 + lrow) * LDAP + kk * 32 + lk8);
            #pragma unroll
            for (int i = 0; i < 4; i++)
                #pragma unroll
                for (int j = 0; j < 2; j++)
                    acc[i][j] = __builtin_amdgcn_mfma_f32_16x16x32_bf16(af[i], bf[j], acc[i][j], 0, 0, 0);
        }
        __syncthreads();
    }
    int col = lane & 15, q4 = (lane >> 4) * 4;
    #pragma unroll
    for (int i = 0; i < 4; i++)
        #pragma unroll
        for (int j = 0; j < 2; j++) {
            int n = n0 + wn * 32 + j * 16 + col;
            #pragma unroll
            for (int r = 0; r < 4; r++) {
                int mm = m0 + wm * 64 + i * 16 + q4 + r;
                D[(size_t)mm * NN + n] = f2b(acc[i][j][r]);
            }
        }
}

// W (permuted cols, zero-padded) -> bf16. rows 0..63 Wr, 64..127 Wu -> Wb; 128..191 Wc -> Wcb
__global__ void wconv_k(const float* __restrict__ Wr, const float* __restrict__ Wu,
                        const float* __restrict__ Wc, unsigned short* __restrict__ Wb,
                        unsigned short* __restrict__ Wcb) {
    int idx = blockIdx.x * 256 + threadIdx.x;   // 192*384
    int row = idx / K2, j = idx - row * K2;
    float v = 0.f;
    if (j < 330) {
        int q = j / CG, rr = j - q * CG;
        int chan = q * CG + (rr < HID ? rr + CIN : rr - HID);
        if (row < 64) v = Wr[row * 330 + chan];
        else if (row < 128) v = Wu[(row - 64) * 330 + chan];
        else v = Wc[(row - 128) * 330 + chan];
    }
    if (row < 128) Wb[row * K2 + j] = f2b(v);
    else Wcb[(row - 128) * K2 + j] = f2b(v);
}

__global__ void zeroz_k(unsigned short* __restrict__ z) {
    size_t i = ((size_t)blockIdx.x * 256 + threadIdx.x) * 8;
    *(short8v*)(z + i) = (short8v){0, 0, 0, 0, 0, 0, 0, 0};
}

// init: h, Z2g self, Abfg rows from h0; x(t=0) into Z2g/Z2c/Abfg/Abfc
__global__ void init_k(const float* __restrict__ x, const float* __restrict__ h0,
                       float* __restrict__ h, unsigned short* __restrict__ Z2g,
                       unsigned short* __restrict__ Z2c, unsigned short* __restrict__ Abfg,
                       unsigned short* __restrict__ Abfc) {
    int m = blockIdx.x * 256 + threadIdx.x;   // 8192
    int b = m >> 10, n = m & 1023;
    for (int c = 0; c < HID; c++) {
        float v = h0[(c << 10) + n];
        h[(size_t)m * HID + c] = v;
        unsigned short hv = f2b(v);
        Z2g[(size_t)m * K2 + c] = hv;
        Abfg[(((size_t)(b * CG + c)) << 10) | n] = hv;
    }
    for (int o = 0; o < CIN; o++) {
        float xv = x[((((size_t)(b * CIN + o)) << 10) + n) * TT];
        unsigned short xb = f2b(xv);
        Z2g[(size_t)m * K2 + HID + o] = xb;
        Z2c[(size_t)m * K2 + HID + o] = xb;
        Abfg[(((size_t)(b * CG + HID + o)) << 10) | n] = xb;
        Abfc[(((size_t)(b * CG + HID + o)) << 10) | n] = xb;
    }
}

// ---------------- per-step kernel bodies (round-12-verbatim, as device fns) ----------------
// 3-buffer depth-2 prefetch pipeline: counted vmcnt (never 0 in main loop),
// one raw s_barrier per K-tile. LDS content: LDS[row][sz] = G[row][sz ^ (row&7)]
// (16B chunks); read chunk cb of row lr at LDS[lr*64 + ((cb ^ (lr&7))<<3)].

// agg tile (operand-swapped): D[(s,n)][bc] = sum_v suppb[s*1024+n][v] * Abf[bc][v]
__device__ __forceinline__ void agg_body(int lin, const unsigned short* __restrict__ S,
                                         const unsigned short* __restrict__ Abf,
                                         unsigned short* __restrict__ Z2,
                                         unsigned short (*lA)[4096], unsigned short (*lB)[4096]) {
    int tid = threadIdx.x;
    // bijective XCD swizzle: 576 = 8 XCDs x 72 tiles
    int swz = (lin & 7) * 72 + (lin >> 3);
    int c0 = (swz % 9) * 64;
    int m0 = (swz / 9) * 64;
    int lane = tid & 63, wave = tid >> 6;
    int wm = wave >> 1, wn = wave & 1;          // wave tile 32m x 32c
    float4v acc[2][2];
    #pragma unroll
    for (int i = 0; i < 2; i++)
        #pragma unroll
        for (int j = 0; j < 2; j++) acc[i][j] = (float4v){0.f, 0.f, 0.f, 0.f};
    int lrow = lane & 15, hi = lane >> 4;

    auto stage = [&](unsigned short* bufA, unsigned short* bufB, int k0) {
        #pragma unroll
        for (int i = 0; i < 2; i++) {
            int cid = (i * 4 + wave) * 64 + lane;
            int r = cid >> 3, sz = cid & 7;
            GLD16(S + (size_t)(m0 + r) * NN + k0 + ((sz ^ (r & 7)) << 3),
                  bufA + (i * 4 + wave) * 512);
        }
        #pragma unroll
        for (int i = 0; i < 2; i++) {
            int cid = (i * 4 + wave) * 64 + lane;
            int r = cid >> 3, sz = cid & 7;
            GLD16(Abf + (((size_t)(c0 + r)) << 10) + k0 + ((sz ^ (r & 7)) << 3),
                  bufB + (i * 4 + wave) * 512);
        }
    };

    unsigned short *a0 = lA[0], *a1 = lA[1], *a2 = lA[2];
    unsigned short *b0 = lB[0], *b1 = lB[1], *b2 = lB[2];
    stage(a0, b0, 0);
    stage(a1, b1, 64);
    for (int kt = 0; kt < 16; kt++) {
        if (kt < 15) asm volatile("s_waitcnt vmcnt(4)" ::: "memory");
        else         asm volatile("s_waitcnt vmcnt(0)" ::: "memory");
        __builtin_amdgcn_s_barrier();
        asm volatile("" ::: "memory");
        if (kt < 14) stage(a2, b2, (kt + 2) * 64);
        #pragma unroll
        for (int kk = 0; kk < 2; kk++) {
            int cb = kk * 4 + hi;
            short8v af[2], bf[2];
            #pragma unroll
            for (int i = 0; i < 2; i++) {
                int lr = wm * 32 + i * 16 + lrow;
                af[i] = *(const short8v*)(a0 + lr * 64 + ((cb ^ (lr & 7)) << 3));
            }
            #pragma unroll
            for (int j = 0; j < 2; j++) {
                int lr = wn * 32 + j * 16 + lrow;
                bf[j] = *(const short8v*)(b0 + lr * 64 + ((cb ^ (lr & 7)) << 3));
            }
            #pragma unroll
            for (int i = 0; i < 2; i++)
                #pragma unroll
                for (int j = 0; j < 2; j++)
                    acc[i][j] = __builtin_amdgcn_mfma_f32_16x16x32_bf16(af[i], bf[j], acc[i][j], 0, 0, 0);
        }
        { unsigned short* t = a0; a0 = a1; a1 = a2; a2 = t; }
        { unsigned short* t = b0; b0 = b1; b1 = b2; b2 = t; }
    }
    int col = lane & 15, q4 = (lane >> 4) * 4;
    int s_idx = m0 >> 10;
    int nb0 = (m0 & 1023) + wm * 32;
    #pragma unroll
    for (int j = 0; j < 2; j++) {
        int bc = c0 + wn * 32 + j * 16 + col;
        if (bc < NBC) {
            int b = bc / CG;
            int rr = bc - b * CG;
            size_t zcol = (size_t)CG + s_idx * CG + rr;
            #pragma unroll
            for (int i = 0; i < 2; i++) {
                int nb = nb0 + i * 16 + q4;
                #pragma unroll
                for (int r = 0; r < 4; r++)
                    Z2[((size_t)((b << 10) | (nb + r))) * K2 + zcol] = f2b(acc[i][j][r]);
            }
        }
    }
}

// gate body (BM=32 cand-style skeleton); isU selects W-half / bias / output path.
__device__ __forceinline__ void gate_body(int m0, int isU,
                                          const unsigned short* __restrict__ Z2g,
                                          const unsigned short* __restrict__ Wb,
                                          const float* __restrict__ br,
                                          const float* __restrict__ bu,
                                          const float* __restrict__ h,
                                          float* __restrict__ u,
                                          unsigned short* __restrict__ Z2c,
                                          unsigned short* __restrict__ Abfc,
                                          unsigned short (*lA)[4096], unsigned short (*lB)[4096]) {
    int tid = threadIdx.x;
    const unsigned short* W = Wb + (size_t)isU * 64 * K2;
    int lane = tid & 63, wave = tid >> 6;
    int wm = wave >> 1, wn = wave & 1;          // wave tile 16m x 32o
    float4v acc[2];
    acc[0] = (float4v){0.f, 0.f, 0.f, 0.f};
    acc[1] = (float4v){0.f, 0.f, 0.f, 0.f};
    int lrow = lane & 15, hi = lane >> 4;

    auto stage = [&](unsigned short* bufA, unsigned short* bufB, int k0) {
        {
            int cid = wave * 64 + lane;         // 256 chunks for 32-row A tile
            int r = cid >> 3, sz = cid & 7;
            GLD16(Z2g + (size_t)(m0 + r) * K2 + k0 + ((sz ^ (r & 7)) << 3),
                  bufA + wave * 512);
        }
        #pragma unroll
        for (int i = 0; i < 2; i++) {
            int cid = (i * 4 + wave) * 64 + lane;
            int r = cid >> 3, sz = cid & 7;
            GLD16(W + (size_t)r * K2 + k0 + ((sz ^ (r & 7)) << 3),
                  bufB + (i * 4 + wave) * 512);
        }
    };

    unsigned short *a0 = lA[0], *a1 = lA[1], *a2 = lA[2];
    unsigned short *b0 = lB[0], *b1 = lB[1], *b2 = lB[2];
    stage(a0, b0, 0);
    stage(a1, b1, 64);
    for (int kt = 0; kt < 6; kt++) {
        if (kt < 5) asm volatile("s_waitcnt vmcnt(3)" ::: "memory");
        else        asm volatile("s_waitcnt vmcnt(0)" ::: "memory");
        __builtin_amdgcn_s_barrier();
        asm volatile("" ::: "memory");
        if (kt < 4) stage(a2, b2, (kt + 2) * 64);
        #pragma unroll
        for (int kk = 0; kk < 2; kk++) {
            int cb = kk * 4 + hi;
            short8v af, bf[2];
            {
                int lr = wm * 16 + lrow;
                af = *(const short8v*)(a0 + lr * 64 + ((cb ^ (lr & 7)) << 3));
            }
            #pragma unroll
            for (int j = 0; j < 2; j++) {
                int lr = wn * 32 + j * 16 + lrow;
                bf[j] = *(const short8v*)(b0 + lr * 64 + ((cb ^ (lr & 7)) << 3));
            }
            #pragma unroll
            for (int j = 0; j < 2; j++)
                acc[j] = __builtin_amdgcn_mfma_f32_16x16x32_bf16(af, bf[j], acc[j], 0, 0, 0);
        }
        { unsigned short* t = a0; a0 = a1; a1 = a2; a2 = t; }
        { unsigned short* t = b0; b0 = b1; b1 = b2; b2 = t; }
    }
    int col = lane & 15, q4 = (lane >> 4) * 4;
    #pragma unroll
    for (int j = 0; j < 2; j++) {
        int oo = wn * 32 + j * 16 + col;
        float bias = isU ? bu[oo] : br[oo];
        #pragma unroll
        for (int r = 0; r < 4; r++) {
            int m = m0 + wm * 16 + q4 + r;
            float g = sigmoidf_(acc[j][r] + bias);
            if (isU) {
                u[(size_t)m * HID + oo] = g;
            } else {
                float rh = g * h[(size_t)m * HID + oo];
                unsigned short hv = f2b(rh);
                Z2c[(size_t)m * K2 + oo] = hv;
                int b = m >> 10, n = m & 1023;
                Abfc[(((size_t)(b * CG + oo)) << 10) | n] = hv;
            }
        }
    }
}

// phase 1 of the step: agg on Abfg (576 blocks)
__global__ __launch_bounds__(256) void agg2_k(const unsigned short* __restrict__ S,
                                              const unsigned short* __restrict__ Abf,
                                              unsigned short* __restrict__ Z2) {
    __shared__ __align__(16) unsigned short lA[3][4096];
    __shared__ __align__(16) unsigned short lB[3][4096];
    agg_body(blockIdx.y * 9 + blockIdx.x, S, Abf, Z2, lA, lB);
}

// phase 2: r-gate only (u moved to phase 3). grid (256).
__global__ __launch_bounds__(256) void gates_r_k(const unsigned short* __restrict__ Z2g,
                                                 const unsigned short* __restrict__ Wb,
                                                 const float* __restrict__ br,
                                                 const float* __restrict__ h,
                                                 unsigned short* __restrict__ Z2c,
                                                 unsigned short* __restrict__ Abfc) {
    __shared__ __align__(16) unsigned short lA[3][4096];
    __shared__ __align__(16) unsigned short lB[3][4096];
    gate_body(blockIdx.x * 32, 0, Z2g, Wb, br, (const float*)0, h, (float*)0,
              Z2c, Abfc, lA, lB);
}

// phase 3: agg on Abfc (blocks 0..575) + u-gate (blocks 576..831); u depends
// only on Z2g (complete since phase 1) so it overlaps the agg tail for free.
__global__ __launch_bounds__(256) void aggu_k(const unsigned short* __restrict__ S,
                                              const unsigned short* __restrict__ Abfc,
                                              unsigned short* __restrict__ Z2c,
                                              const unsigned short* __restrict__ Z2g,
                                              const unsigned short* __restrict__ Wb,
                                              const float* __restrict__ bu,
                                              float* __restrict__ u) {
    __shared__ __align__(16) unsigned short lA[3][4096];
    __shared__ __align__(16) unsigned short lB[3][4096];
    if (blockIdx.x < 576)
        agg_body(blockIdx.x, S, Abfc, Z2c, lA, lB);
    else
        gate_body((blockIdx.x - 576) * 32, 1, Z2g, Wb, (const float*)0, bu,
                  (const float*)0, u, (unsigned short*)0, (unsigned short*)0, lA, lB);
}

// cand: cv = tanh(Wc·Z2c + bc); hraw = u*h + (1-u)*cv; per-block GN partial sums.
// BM=32 -> grid (256). NT=6, P=3.
__global__ __launch_bounds__(256) void cand_k2(const unsigned short* __restrict__ Z2c,
                                               const unsigned short* __restrict__ Wcb,
                                               const float* __restrict__ bcv,
                                               const float* __restrict__ u,
                                               const float* __restrict__ h,
                                               float* __restrict__ hraw,
                                               float* __restrict__ stats2, int t) {
    __shared__ __align__(16) unsigned short lA[3][32 * 64];
    __shared__ __align__(16) unsigned short lB[3][64 * 64];
    int tid = threadIdx.x;
    int m0 = blockIdx.x * 32;
    int lane = tid & 63, wave = tid >> 6;
    int wm = wave >> 1, wn = wave & 1;          // wave tile 16m x 32o
    float4v acc[2];
    acc[0] = (float4v){0.f, 0.f, 0.f, 0.f};
    acc[1] = (float4v){0.f, 0.f, 0.f, 0.f};
    int lrow = lane & 15, hi = lane >> 4;

    auto stage = [&](unsigned short* bufA, unsigned short* bufB, int k0) {
        {
            int cid = wave * 64 + lane;
            int r = cid >> 3, sz = cid & 7;
            GLD16(Z2c + (size_t)(m0 + r) * K2 + k0 + ((sz ^ (r & 7)) << 3),
                  bufA + wave * 512);
        }
        #pragma unroll
        for (int i = 0; i < 2; i++) {
            int cid = (i * 4 + wave) * 64 + lane;
            int r = cid >> 3, sz = cid & 7;
            GLD16(Wcb + (size_t)r * K2 + k0 + ((sz ^ (r & 7)) << 3),
                  bufB + (i * 4 + wave) * 512);
        }
    };

    unsigned short *a0 = lA[0], *a1 = lA[1], *a2 = lA[2];
    unsigned short *b0 = lB[0], *b1 = lB[1], *b2 = lB[2];
    stage(a0, b0, 0);
    stage(a1, b1, 64);
    for (int kt = 0; kt < 6; kt++) {
        if (kt < 5) asm volatile("s_waitcnt vmcnt(3)" ::: "memory");
        else        asm volatile("s_waitcnt vmcnt(0)" ::: "memory");
        __builtin_amdgcn_s_barrier();
        asm volatile("" ::: "memory");
        if (kt < 4) stage(a2, b2, (kt + 2) * 64);
        #pragma unroll
        for (int kk = 0; kk < 2; kk++) {
            int cb = kk * 4 + hi;
            short8v af, bf[2];
            {
                int lr = wm * 16 + lrow;
                af = *(const short8v*)(a0 + lr * 64 + ((cb ^ (lr & 7)) << 3));
            }
            #pragma unroll
            for (int j = 0; j < 2; j++) {
                int lr = wn * 32 + j * 16 + lrow;
                bf[j] = *(const short8v*)(b0 + lr * 64 + ((cb ^ (lr & 7)) << 3));
            }
            #pragma unroll
            for (int j = 0; j < 2; j++)
                acc[j] = __builtin_amdgcn_mfma_f32_16x16x32_bf16(af, bf[j], acc[j], 0, 0, 0);
        }
        { unsigned short* t_ = a0; a0 = a1; a1 = a2; a2 = t_; }
        { unsigned short* t_ = b0; b0 = b1; b1 = b2; b2 = t_; }
    }
    int col = lane & 15, q4 = (lane >> 4) * 4;
    float ls = 0.f, ls2 = 0.f;
    #pragma unroll
    for (int j = 0; j < 2; j++) {
        int oo = wn * 32 + j * 16 + col;
        float bias = bcv[oo];
        #pragma unroll
        for (int r = 0; r < 4; r++) {
            int m = m0 + wm * 16 + q4 + r;
            float cv = tanhf(acc[j][r] + bias);
            float uv = u[(size_t)m * HID + oo];
            float hv = h[(size_t)m * HID + oo];
            float hr = uv * hv + (1.f - uv) * cv;
            hraw[(size_t)m * HID + oo] = hr;
            ls += hr;
            ls2 = fmaf(hr, hr, ls2);
        }
    }
    ls = wave_reduce_sum(ls);
    ls2 = wave_reduce_sum(ls2);
    __shared__ float sred[8];
    if (lane == 0) { sred[wave] = ls; sred[4 + wave] = ls2; }
    __syncthreads();
    if (tid == 0) {
        float S = sred[0] + sred[1] + sred[2] + sred[3];
        float S2 = sred[4] + sred[5] + sred[6] + sred[7];
        int b = blockIdx.x >> 5, slot = blockIdx.x & 31;
        float* dst = stats2 + (((size_t)t * BB + b) * 32 + slot) * 2;
        dst[0] = S;
        dst[1] = S2;
    }
}

// apply: GN + h update + x_hat + next-step build. 8 threads per m. grid (256).
__global__ __launch_bounds__(256) void apply_k2(const float* __restrict__ hraw,
                                                const float* __restrict__ stats2,
                                                const float* __restrict__ gamma,
                                                const float* __restrict__ beta,
                                                const float* __restrict__ Wo,
                                                const float* __restrict__ bo,
                                                const float* __restrict__ x,
                                                float* __restrict__ h,
                                                unsigned short* __restrict__ Z2g,
                                                unsigned short* __restrict__ Z2c,
                                                unsigned short* __restrict__ Abfg,
                                                unsigned short* __restrict__ Abfc,
                                                unsigned short* __restrict__ hseq8,
                                                float* __restrict__ iseq, int t) {
    int gid = blockIdx.x * 256 + threadIdx.x;   // 65536
    int m = gid >> 3, q = gid & 7;
    int b = m >> 10, n = m & 1023;
    const float* st = stats2 + ((size_t)t * BB + b) * 64;
    float S = 0.f, S2 = 0.f;
    #pragma unroll
    for (int i = 0; i < 16; i++) {
        float4 p4 = *(const float4*)&st[i * 4];
        S += p4.x + p4.z;
        S2 += p4.y + p4.w;
    }
    float mean = S * (1.f / 65536.f);
    float rstd = rsqrtf(S2 * (1.f / 65536.f) - mean * mean + GN_EPS);
    bool more = (t < TT - 1);
    int c0 = q * 8;
    float v[8];
    unsigned short hb[8];
    #pragma unroll
    for (int k = 0; k < 8; k += 4) {
        float4 r4 = *(const float4*)&hraw[(size_t)m * HID + c0 + k];
        v[k + 0] = (r4.x - mean) * rstd * gamma[c0 + k + 0] + beta[c0 + k + 0];
        v[k + 1] = (r4.y - mean) * rstd * gamma[c0 + k + 1] + beta[c0 + k + 1];
        v[k + 2] = (r4.z - mean) * rstd * gamma[c0 + k + 2] + beta[c0 + k + 2];
        v[k + 3] = (r4.w - mean) * rstd * gamma[c0 + k + 3] + beta[c0 + k + 3];
    }
    float acc0 = 0.f, acc1 = 0.f;
    #pragma unroll
    for (int k = 0; k < 8; k++) {
        acc0 = fmaf(Wo[c0 + k], v[k], acc0);
        acc1 = fmaf(Wo[HID + c0 + k], v[k], acc1);
        hb[k] = f2b(v[k]);
    }
    short8v h8;
    #pragma unroll
    for (int k = 0; k < 8; k++) h8[k] = (short)hb[k];
    size_t hsbase = ((size_t)(t & 7) * 8192 + m) * HID + c0;
    *(short8v*)&hseq8[hsbase] = h8;
    if (more) {
        #pragma unroll
        for (int k = 0; k < 8; k += 4)
            *(float4*)&h[(size_t)m * HID + c0 + k] = make_float4(v[k], v[k + 1], v[k + 2], v[k + 3]);
        *(short8v*)&Z2g[(size_t)m * K2 + c0] = h8;
        #pragma unroll
        for (int k = 0; k < 8; k++)
            Abfg[(((size_t)(b * CG + c0 + k)) << 10) | n] = hb[k];
    }
    acc0 += __shfl_xor(acc0, 1, 64); acc0 += __shfl_xor(acc0, 2, 64); acc0 += __shfl_xor(acc0, 4, 64);
    acc1 += __shfl_xor(acc1, 1, 64); acc1 += __shfl_xor(acc1, 2, 64); acc1 += __shfl_xor(acc1, 4, 64);
    if (q == 0) {
        iseq[((size_t)t * 8192 + m) * 2 + 0] = acc0 + bo[0];
        iseq[((size_t)t * 8192 + m) * 2 + 1] = acc1 + bo[1];
        if (more) {
            #pragma unroll
            for (int o = 0; o < CIN; o++) {
                float xv = x[((((size_t)(b * CIN + o)) << 10) + n) * TT + t + 1];
                unsigned short xb = f2b(xv);
                Z2g[(size_t)m * K2 + HID + o] = xb;
                Z2c[(size_t)m * K2 + HID + o] = xb;
                Abfg[(((size_t)(b * CG + HID + o)) << 10) | n] = xb;
                Abfc[(((size_t)(b * CG + HID + o)) << 10) | n] = xb;
            }
        }
    }
}

// states chunk transpose: hseq8 [8][8192][64] bf16 -> out_states [b][c][n][t0..t0+7] f32
__global__ __launch_bounds__(256) void strans_k(const unsigned short* __restrict__ hseq8,
                                                float* __restrict__ outS, int t0) {
    __shared__ unsigned short lt[8 * 576];      // [tt][dn][c], dn stride 72
    int tid = threadIdx.x;
    int b = blockIdx.x >> 7;
    int n0 = (blockIdx.x & 127) * 8;
    #pragma unroll
    for (int s = 0; s < 2; s++) {
        int slot = tid + s * 256;               // 512 chunks of 8 shorts
        int tt = slot >> 6, dn = (slot >> 3) & 7, kc = slot & 7;
        short8v vv = *(const short8v*)(hseq8 + ((size_t)tt * 8192 + ((b << 10) | (n0 + dn))) * HID + kc * 8);
        *(short8v*)(lt + tt * 576 + dn * 72 + kc * 8) = vv;
    }
    __syncthreads();
    #pragma unroll
    for (int s = 0; s < 2; s++) {
        int rid = tid + s * 256;                // (c, dn)
        int c = rid >> 3, dn = rid & 7;
        float f[8];
        #pragma unroll
        for (int tt = 0; tt < 8; tt++) f[tt] = b2f(lt[tt * 576 + dn * 72 + c]);
        float* dst = outS + ((((size_t)(b * HID + c)) << 10) + n0 + dn) * TT + t0;
        *(float4*)&dst[0] = make_float4(f[0], f[1], f[2], f[3]);
        *(float4*)&dst[4] = make_float4(f[4], f[5], f[6], f[7]);
    }
}

// imputations transpose: iseq [32][8192][2] -> out [b][o][n][t]
__global__ void itrans_k(const float* __restrict__ iseq, float* __restrict__ out) {
    int gid = blockIdx.x * 256 + threadIdx.x;   // 16384
    int b = gid >> 11, o = (gid >> 10) & 1, n = gid & 1023;
    float f[TT];
    #pragma unroll
    for (int t = 0; t < TT; t++)
        f[t] = iseq[((size_t)t * 8192 + ((b << 10) | n)) * 2 + o];
    float* dst = out + ((((size_t)(b * CIN + o)) << 10) + n) * TT;
    #pragma unroll
    for (int k = 0; k < TT; k += 4)
        *(float4*)&dst[k] = make_float4(f[k], f[k + 1], f[k + 2], f[k + 3]);
}

// ---------------- launch ----------------

extern "C" void kernel_launch(void* const* d_in, const int* in_sizes, int n_in,
                              void* d_out, int out_size, void* d_ws, size_t ws_size,
                              hipStream_t stream) {
    const float* x     = (const float*)d_in[0];
    const float* adj   = (const float*)d_in[1];
    const float* h0    = (const float*)d_in[2];
    const float* Wr    = (const float*)d_in[3];
    const float* br    = (const float*)d_in[4];
    const float* Wu    = (const float*)d_in[5];
    const float* bu    = (const float*)d_in[6];
    const float* Wc    = (const float*)d_in[7];
    const float* bcv   = (const float*)d_in[8];
    const float* gamma = (const float*)d_in[9];
    const float* beta  = (const float*)d_in[10];
    const float* Wo    = (const float*)d_in[11];
    const float* bo    = (const float*)d_in[12];
    float* out = (float*)d_out;

    char* p = (char*)d_ws;
    unsigned short* suppb = (unsigned short*)p;  p += (size_t)4 * NN * NN * 2;          // 8 MB
    unsigned short* Abfg  = (unsigned short*)p;  p += (size_t)576 * NN * 2;
    unsigned short* Abfc  = (unsigned short*)p;  p += (size_t)576 * NN * 2;
    unsigned short* Z2g   = (unsigned short*)p;  p += (size_t)8192 * K2 * 2;
    unsigned short* Z2c   = (unsigned short*)p;  p += (size_t)8192 * K2 * 2;            // adjacent to Z2g
    unsigned short* Wb    = (unsigned short*)p;  p += (size_t)128 * K2 * 2;
    unsigned short* Wcb   = (unsigned short*)p;  p += (size_t)64 * K2 * 2;
    float* u     = (float*)p;  p += (size_t)8192 * HID * 4;
    float* h     = (float*)p;  p += (size_t)8192 * HID * 4;
    float* hraw  = (float*)p;  p += (size_t)8192 * HID * 4;
    unsigned short* hseq8 = (unsigned short*)p;  p += (size_t)8 * 8192 * HID * 2;       // 8 MB
    float* iseq  = (float*)p;  p += (size_t)TT * 8192 * 2 * 4;
    float* rowsum = (float*)p; p += NN * 4;
    float* cpart  = (float*)p; p += (size_t)8 * NN * 4;
    float* stats2 = (float*)p; p += (size_t)TT * BB * 32 * 2 * 4;

    float* outS = out + (size_t)BB * CIN * NN * TT;

    rowsum_k<<<NN, 256, 0, stream>>>(adj, rowsum);
    colsum_k<<<32, 256, 0, stream>>>(adj, cpart);
    fwdb_k<<<(NN * NN) / 256, 256, 0, stream>>>(adj, rowsum, suppb);
    bwdb_k<<<dim3(32, 32), dim3(32, 8), 0, stream>>>(adj, cpart, suppb + (size_t)NN * NN);
    suppk_mfma<<<dim3(8, 16, 2), 256, 0, stream>>>(suppb, suppb + (size_t)2 * NN * NN);
    wconv_k<<<(192 * K2) / 256, 256, 0, stream>>>(Wr, Wu, Wc, Wb, Wcb);
    zeroz_k<<<(2 * 8192 * K2) / (8 * 256), 256, 0, stream>>>(Z2g);
    init_k<<<8192 / 256, 256, 0, stream>>>(x, h0, h, Z2g, Z2c, Abfg, Abfc);

    for (int t = 0; t < TT; t++) {
        agg2_k<<<dim3(9, 64), 256, 0, stream>>>(suppb, Abfg, Z2g);
        gates_r_k<<<256, 256, 0, stream>>>(Z2g, Wb, br, h, Z2c, Abfc);
        aggu_k<<<832, 256, 0, stream>>>(suppb, Abfc, Z2c, Z2g, Wb, bu, u);
        cand_k2<<<256, 256, 0, stream>>>(Z2c, Wcb, bcv, u, h, hraw, stats2, t);
        apply_k2<<<256, 256, 0, stream>>>(hraw, stats2, gamma, beta, Wo, bo, x, h,
                                          Z2g, Z2c, Abfg, Abfc, hseq8, iseq, t);
        if ((t & 7) == 7)
            strans_k<<<1024, 256, 0, stream>>>(hseq8, outS, t - 7);
    }
    itrans_k<<<64, 256, 0, stream>>>(iseq, out);
}

// Round 15
// 1362.311 us; speedup vs baseline: 1.2919x; 1.0130x over previous
//
#include <hip/hip_runtime.h>
#include <math.h>

#define NN 1024
#define HID 64
#define CIN 2
#define BB 8
#define TT 32
#define CG 66            // channels per support block, stored as [h0..h63,x0,x1]
#define NBC 528          // 8 * 66 channel rows in Abf
#define K2 384           // padded conv-channel count (330 -> 384)
#define GN_EPS 1e-5f
#define LDAP 72

typedef __attribute__((ext_vector_type(8))) short short8v;
typedef __attribute__((ext_vector_type(4))) float float4v;

// async global->LDS, 16B per lane. Dest is wave-uniform base + lane*16.
#define GLD16(gp, lp) __builtin_amdgcn_global_load_lds( \
    (const __attribute__((address_space(1))) void*)(gp), \
    (__attribute__((address_space(3))) void*)(lp), 16, 0, 0)

__device__ __forceinline__ unsigned short f2b(float v) {
    union { float f; unsigned int u; } a; a.f = v;
    unsigned int r = a.u + 0x7FFFu + ((a.u >> 16) & 1u);
    return (unsigned short)(r >> 16);
}
__device__ __forceinline__ float b2f(unsigned short b) {
    union { unsigned int u; float f; } a; a.u = ((unsigned int)b) << 16;
    return a.f;
}
__device__ __forceinline__ float sigmoidf_(float v) { return 1.f / (1.f + __expf(-v)); }

__device__ __forceinline__ float wave_reduce_sum(float v) {
    #pragma unroll
    for (int o = 32; o > 0; o >>= 1) v += __shfl_down(v, o, 64);
    return v;
}

// ---------------- one-time precompute ----------------

__global__ void rowsum_k(const float* __restrict__ adj, float* __restrict__ rs) {
    int i = blockIdx.x;
    float s = 0.f;
    for (int j = threadIdx.x; j < NN; j += 256) s += adj[(size_t)i * NN + j];
    s = wave_reduce_sum(s);
    __shared__ float sh[4];
    int wid = threadIdx.x >> 6, lid = threadIdx.x & 63;
    if (lid == 0) sh[wid] = s;
    __syncthreads();
    if (threadIdx.x == 0) rs[i] = sh[0] + sh[1] + sh[2] + sh[3];
}

// deterministic column-sum partials: cpart[chunk][j] = sum of rows chunk*128..+127
__global__ void colsum_k(const float* __restrict__ adj, float* __restrict__ cpart) {
    int j = (blockIdx.x & 3) * 256 + threadIdx.x;
    int r0 = (blockIdx.x >> 2) * 128;
    float s = 0.f;
    for (int i = 0; i < 128; i++) s += adj[(size_t)(r0 + i) * NN + j];
    cpart[(size_t)(blockIdx.x >> 2) * NN + j] = s;
}

// suppb[0] = fwd (bf16)
__global__ void fwdb_k(const float* __restrict__ adj, const float* __restrict__ rs,
                       unsigned short* __restrict__ sb) {
    int idx = blockIdx.x * 256 + threadIdx.x;
    int i = idx >> 10;
    sb[idx] = f2b(adj[idx] / (rs[i] + 1e-8f));
}

// suppb[1] = bwd (bf16): bwd[i][j] = adj[j][i]/(colsum[i]+1e-8)
__global__ void bwdb_k(const float* __restrict__ adj, const float* __restrict__ cpart,
                       unsigned short* __restrict__ sb) {
    __shared__ float tile[32][33];
    int i0 = blockIdx.y * 32, j0 = blockIdx.x * 32;
    int tx = threadIdx.x, ty = threadIdx.y;   // 32 x 8
    #pragma unroll
    for (int r = ty; r < 32; r += 8)
        tile[r][tx] = adj[(size_t)(j0 + r) * NN + i0 + tx];
    __syncthreads();
    #pragma unroll
    for (int r = ty; r < 32; r += 8) {
        int i = i0 + r;
        float cs = 0.f;
        #pragma unroll
        for (int c = 0; c < 8; c++) cs += cpart[(size_t)c * NN + i];
        sb[(size_t)i * NN + j0 + tx] = f2b(tile[tx][r] / (cs + 1e-8f));
    }
}

// suppb[2+z] = suppb[z] @ suppb[z]^T, bf16 MFMA NT. grid (8,16,2), 256 thr.
__global__ __launch_bounds__(256) void suppk_mfma(const unsigned short* __restrict__ sb,
                                                  unsigned short* __restrict__ outb) {
    int z = blockIdx.z;
    const unsigned short* A = sb + (size_t)z * NN * NN;
    unsigned short* D = outb + (size_t)z * NN * NN;
    __shared__ unsigned short lA[128 * LDAP];
    __shared__ unsigned short lB[64 * LDAP];
    int tid = threadIdx.x;
    int m0 = blockIdx.x * 128, n0 = blockIdx.y * 64;
    int lane = tid & 63, wave = tid >> 6;
    int wm = wave >> 1, wn = wave & 1;          // wave tile 64m x 32n
    float4v acc[4][2];
    #pragma unroll
    for (int i = 0; i < 4; i++)
        #pragma unroll
        for (int j = 0; j < 2; j++) acc[i][j] = (float4v){0.f, 0.f, 0.f, 0.f};
    int lrow = lane & 15, lk8 = (lane >> 4) * 8;
    for (int k0 = 0; k0 < NN; k0 += 64) {
        #pragma unroll
        for (int s = 0; s < 4; s++) {
            int slot = tid + s * 256;
            int r = slot >> 3, kg = slot & 7;
            *(short8v*)(lA + r * LDAP + kg * 8) =
                *(const short8v*)(A + (size_t)(m0 + r) * NN + k0 + kg * 8);
        }
        #pragma unroll
        for (int s = 0; s < 2; s++) {
            int slot = tid + s * 256;
            int r = slot >> 3, kg = slot & 7;
            *(short8v*)(lB + r * LDAP + kg * 8) =
                *(const short8v*)(A + (size_t)(n0 + r) * NN + k0 + kg * 8);
        }
        __syncthreads();
        #pragma unroll
        for (int kk = 0; kk < 2; kk++) {
            short8v af[4], bf[2];
            #pragma unroll
            for (int i = 0; i < 4; i++)
                af[i] = *(const short8v*)(lA + (wm * 64 + i * 16 + lrow) * LDAP + kk * 32 + lk8);
            #pragma unroll
            for (int j = 0; j < 2; j++)
                bf[j] = *(const short8v*)(lB + (wn * 32 + j * 16 + lrow) * LDAP + kk * 32 + lk8);
            #pragma unroll
            for (int i = 0; i < 4; i++)
                #pragma unroll
                for (int j = 0; j < 2; j++)
                    acc[i][j] = __builtin_amdgcn_mfma_f32_16x16x32_bf16(af[i], bf[j], acc[i][j], 0, 0, 0);
        }
        __syncthreads();
    }
    int col = lane & 15, q4 = (lane >> 4) * 4;
    #pragma unroll
    for (int i = 0; i < 4; i++)
        #pragma unroll
        for (int j = 0; j < 2; j++) {
            int n = n0 + wn * 32 + j * 16 + col;
            #pragma unroll
            for (int r = 0; r < 4; r++) {
                int mm = m0 + wm * 64 + i * 16 + q4 + r;
                D[(size_t)mm * NN + n] = f2b(acc[i][j][r]);
            }
        }
}

// W (permuted cols, zero-padded) -> bf16. rows 0..63 Wr, 64..127 Wu -> Wb; 128..191 Wc -> Wcb
__global__ void wconv_k(const float* __restrict__ Wr, const float* __restrict__ Wu,
                        const float* __restrict__ Wc, unsigned short* __restrict__ Wb,
                        unsigned short* __restrict__ Wcb) {
    int idx = blockIdx.x * 256 + threadIdx.x;   // 192*384
    int row = idx / K2, j = idx - row * K2;
    float v = 0.f;
    if (j < 330) {
        int q = j / CG, rr = j - q * CG;
        int chan = q * CG + (rr < HID ? rr + CIN : rr - HID);
        if (row < 64) v = Wr[row * 330 + chan];
        else if (row < 128) v = Wu[(row - 64) * 330 + chan];
        else v = Wc[(row - 128) * 330 + chan];
    }
    if (row < 128) Wb[row * K2 + j] = f2b(v);
    else Wcb[(row - 128) * K2 + j] = f2b(v);
}

__global__ void zeroz_k(unsigned short* __restrict__ z) {
    size_t i = ((size_t)blockIdx.x * 256 + threadIdx.x) * 8;
    *(short8v*)(z + i) = (short8v){0, 0, 0, 0, 0, 0, 0, 0};
}

// init: h, Z2g self, Abfg rows from h0; x(t=0) into Z2g/Z2c/Abfg/Abfc
__global__ void init_k(const float* __restrict__ x, const float* __restrict__ h0,
                       float* __restrict__ h, unsigned short* __restrict__ Z2g,
                       unsigned short* __restrict__ Z2c, unsigned short* __restrict__ Abfg,
                       unsigned short* __restrict__ Abfc) {
    int m = blockIdx.x * 256 + threadIdx.x;   // 8192
    int b = m >> 10, n = m & 1023;
    for (int c = 0; c < HID; c++) {
        float v = h0[(c << 10) + n];
        h[(size_t)m * HID + c] = v;
        unsigned short hv = f2b(v);
        Z2g[(size_t)m * K2 + c] = hv;
        Abfg[(((size_t)(b * CG + c)) << 10) | n] = hv;
    }
    for (int o = 0; o < CIN; o++) {
        float xv = x[((((size_t)(b * CIN + o)) << 10) + n) * TT];
        unsigned short xb = f2b(xv);
        Z2g[(size_t)m * K2 + HID + o] = xb;
        Z2c[(size_t)m * K2 + HID + o] = xb;
        Abfg[(((size_t)(b * CG + HID + o)) << 10) | n] = xb;
        Abfc[(((size_t)(b * CG + HID + o)) << 10) | n] = xb;
    }
}

// ---------------- per-step kernel bodies ----------------
// 3-buffer depth-2 prefetch pipeline: counted vmcnt (never 0 in main loop),
// one raw s_barrier per K-tile. LDS content: LDS[row][sz] = G[row][sz ^ (row&7)]
// (16B chunks); read chunk cb of row lr at LDS[lr*64 + ((cb ^ (lr&7))<<3)].

// agg tile (operand-swapped): D[(s,n)][bc] = sum_v suppb[s*1024+n][v] * Abf[bc][v]
__device__ __forceinline__ void agg_body(int lin, const unsigned short* __restrict__ S,
                                         const unsigned short* __restrict__ Abf,
                                         unsigned short* __restrict__ Z2,
                                         unsigned short (*lA)[4096], unsigned short (*lB)[4096]) {
    int tid = threadIdx.x;
    // bijective XCD swizzle: 576 = 8 XCDs x 72 tiles
    int swz = (lin & 7) * 72 + (lin >> 3);
    int c0 = (swz % 9) * 64;
    int m0 = (swz / 9) * 64;
    int lane = tid & 63, wave = tid >> 6;
    int wm = wave >> 1, wn = wave & 1;          // wave tile 32m x 32c
    float4v acc[2][2];
    #pragma unroll
    for (int i = 0; i < 2; i++)
        #pragma unroll
        for (int j = 0; j < 2; j++) acc[i][j] = (float4v){0.f, 0.f, 0.f, 0.f};
    int lrow = lane & 15, hi = lane >> 4;

    auto stage = [&](unsigned short* bufA, unsigned short* bufB, int k0) {
        #pragma unroll
        for (int i = 0; i < 2; i++) {
            int cid = (i * 4 + wave) * 64 + lane;
            int r = cid >> 3, sz = cid & 7;
            GLD16(S + (size_t)(m0 + r) * NN + k0 + ((sz ^ (r & 7)) << 3),
                  bufA + (i * 4 + wave) * 512);
        }
        #pragma unroll
        for (int i = 0; i < 2; i++) {
            int cid = (i * 4 + wave) * 64 + lane;
            int r = cid >> 3, sz = cid & 7;
            GLD16(Abf + (((size_t)(c0 + r)) << 10) + k0 + ((sz ^ (r & 7)) << 3),
                  bufB + (i * 4 + wave) * 512);
        }
    };

    unsigned short *a0 = lA[0], *a1 = lA[1], *a2 = lA[2];
    unsigned short *b0 = lB[0], *b1 = lB[1], *b2 = lB[2];
    stage(a0, b0, 0);
    stage(a1, b1, 64);
    for (int kt = 0; kt < 16; kt++) {
        if (kt < 15) asm volatile("s_waitcnt vmcnt(4)" ::: "memory");
        else         asm volatile("s_waitcnt vmcnt(0)" ::: "memory");
        __builtin_amdgcn_s_barrier();
        asm volatile("" ::: "memory");
        if (kt < 14) stage(a2, b2, (kt + 2) * 64);
        #pragma unroll
        for (int kk = 0; kk < 2; kk++) {
            int cb = kk * 4 + hi;
            short8v af[2], bf[2];
            #pragma unroll
            for (int i = 0; i < 2; i++) {
                int lr = wm * 32 + i * 16 + lrow;
                af[i] = *(const short8v*)(a0 + lr * 64 + ((cb ^ (lr & 7)) << 3));
            }
            #pragma unroll
            for (int j = 0; j < 2; j++) {
                int lr = wn * 32 + j * 16 + lrow;
                bf[j] = *(const short8v*)(b0 + lr * 64 + ((cb ^ (lr & 7)) << 3));
            }
            #pragma unroll
            for (int i = 0; i < 2; i++)
                #pragma unroll
                for (int j = 0; j < 2; j++)
                    acc[i][j] = __builtin_amdgcn_mfma_f32_16x16x32_bf16(af[i], bf[j], acc[i][j], 0, 0, 0);
        }
        { unsigned short* t = a0; a0 = a1; a1 = a2; a2 = t; }
        { unsigned short* t = b0; b0 = b1; b1 = b2; b2 = t; }
    }
    int col = lane & 15, q4 = (lane >> 4) * 4;
    int s_idx = m0 >> 10;
    int nb0 = (m0 & 1023) + wm * 32;
    #pragma unroll
    for (int j = 0; j < 2; j++) {
        int bc = c0 + wn * 32 + j * 16 + col;
        if (bc < NBC) {
            int b = bc / CG;
            int rr = bc - b * CG;
            size_t zcol = (size_t)CG + s_idx * CG + rr;
            #pragma unroll
            for (int i = 0; i < 2; i++) {
                int nb = nb0 + i * 16 + q4;
                #pragma unroll
                for (int r = 0; r < 4; r++)
                    Z2[((size_t)((b << 10) | (nb + r))) * K2 + zcol] = f2b(acc[i][j][r]);
            }
        }
    }
}

// gate body (BM=32 cand-style skeleton); isU selects W-half / bias / output path.
__device__ __forceinline__ void gate_body(int m0, int isU,
                                          const unsigned short* __restrict__ Z2g,
                                          const unsigned short* __restrict__ Wb,
                                          const float* __restrict__ br,
                                          const float* __restrict__ bu,
                                          const float* __restrict__ h,
                                          float* __restrict__ u,
                                          unsigned short* __restrict__ Z2c,
                                          unsigned short* __restrict__ Abfc,
                                          unsigned short (*lA)[4096], unsigned short (*lB)[4096]) {
    int tid = threadIdx.x;
    const unsigned short* W = Wb + (size_t)isU * 64 * K2;
    int lane = tid & 63, wave = tid >> 6;
    int wm = wave >> 1, wn = wave & 1;          // wave tile 16m x 32o
    float4v acc[2];
    acc[0] = (float4v){0.f, 0.f, 0.f, 0.f};
    acc[1] = (float4v){0.f, 0.f, 0.f, 0.f};
    int lrow = lane & 15, hi = lane >> 4;

    auto stage = [&](unsigned short* bufA, unsigned short* bufB, int k0) {
        {
            int cid = wave * 64 + lane;         // 256 chunks for 32-row A tile
            int r = cid >> 3, sz = cid & 7;
            GLD16(Z2g + (size_t)(m0 + r) * K2 + k0 + ((sz ^ (r & 7)) << 3),
                  bufA + wave * 512);
        }
        #pragma unroll
        for (int i = 0; i < 2; i++) {
            int cid = (i * 4 + wave) * 64 + lane;
            int r = cid >> 3, sz = cid & 7;
            GLD16(W + (size_t)r * K2 + k0 + ((sz ^ (r & 7)) << 3),
                  bufB + (i * 4 + wave) * 512);
        }
    };

    unsigned short *a0 = lA[0], *a1 = lA[1], *a2 = lA[2];
    unsigned short *b0 = lB[0], *b1 = lB[1], *b2 = lB[2];
    stage(a0, b0, 0);
    stage(a1, b1, 64);
    for (int kt = 0; kt < 6; kt++) {
        if (kt < 5) asm volatile("s_waitcnt vmcnt(3)" ::: "memory");
        else        asm volatile("s_waitcnt vmcnt(0)" ::: "memory");
        __builtin_amdgcn_s_barrier();
        asm volatile("" ::: "memory");
        if (kt < 4) stage(a2, b2, (kt + 2) * 64);
        #pragma unroll
        for (int kk = 0; kk < 2; kk++) {
            int cb = kk * 4 + hi;
            short8v af, bf[2];
            {
                int lr = wm * 16 + lrow;
                af = *(const short8v*)(a0 + lr * 64 + ((cb ^ (lr & 7)) << 3));
            }
            #pragma unroll
            for (int j = 0; j < 2; j++) {
                int lr = wn * 32 + j * 16 + lrow;
                bf[j] = *(const short8v*)(b0 + lr * 64 + ((cb ^ (lr & 7)) << 3));
            }
            #pragma unroll
            for (int j = 0; j < 2; j++)
                acc[j] = __builtin_amdgcn_mfma_f32_16x16x32_bf16(af, bf[j], acc[j], 0, 0, 0);
        }
        { unsigned short* t = a0; a0 = a1; a1 = a2; a2 = t; }
        { unsigned short* t = b0; b0 = b1; b1 = b2; b2 = t; }
    }
    int col = lane & 15, q4 = (lane >> 4) * 4;
    #pragma unroll
    for (int j = 0; j < 2; j++) {
        int oo = wn * 32 + j * 16 + col;
        float bias = isU ? bu[oo] : br[oo];
        #pragma unroll
        for (int r = 0; r < 4; r++) {
            int m = m0 + wm * 16 + q4 + r;
            float g = sigmoidf_(acc[j][r] + bias);
            if (isU) {
                u[(size_t)m * HID + oo] = g;
            } else {
                float rh = g * h[(size_t)m * HID + oo];
                unsigned short hv = f2b(rh);
                Z2c[(size_t)m * K2 + oo] = hv;
                int b = m >> 10, n = m & 1023;
                Abfc[(((size_t)(b * CG + oo)) << 10) | n] = hv;
            }
        }
    }
}

// strans body: hseq8 [8][8192][64] bf16 -> out_states [b][c][n][t0..t0+7] f32
__device__ __forceinline__ void strans_body(int tile, const unsigned short* __restrict__ hseq8,
                                            float* __restrict__ outS, int t0,
                                            unsigned short* lt) {
    __syncthreads();                            // protect lt reuse across tiles
    int tid = threadIdx.x;
    int b = tile >> 7;
    int n0 = (tile & 127) * 8;
    #pragma unroll
    for (int s = 0; s < 2; s++) {
        int slot = tid + s * 256;               // 512 chunks of 8 shorts
        int tt = slot >> 6, dn = (slot >> 3) & 7, kc = slot & 7;
        short8v vv = *(const short8v*)(hseq8 + ((size_t)tt * 8192 + ((b << 10) | (n0 + dn))) * HID + kc * 8);
        *(short8v*)(lt + tt * 576 + dn * 72 + kc * 8) = vv;
    }
    __syncthreads();
    #pragma unroll
    for (int s = 0; s < 2; s++) {
        int rid = tid + s * 256;                // (c, dn)
        int c = rid >> 3, dn = rid & 7;
        float f[8];
        #pragma unroll
        for (int tt = 0; tt < 8; tt++) f[tt] = b2f(lt[tt * 576 + dn * 72 + c]);
        float* dst = outS + ((((size_t)(b * HID + c)) << 10) + n0 + dn) * TT + t0;
        *(float4*)&dst[0] = make_float4(f[0], f[1], f[2], f[3]);
        *(float4*)&dst[4] = make_float4(f[4], f[5], f[6], f[7]);
    }
}

// itrans body: iseq [32][8192][2] -> out [b][o][n][t]
__device__ __forceinline__ void itrans_body(int tile, const float* __restrict__ iseq,
                                            float* __restrict__ out) {
    int gid = tile * 256 + threadIdx.x;
    int b = gid >> 11, o = (gid >> 10) & 1, n = gid & 1023;
    float f[TT];
    #pragma unroll
    for (int t = 0; t < TT; t++)
        f[t] = iseq[((size_t)t * 8192 + ((b << 10) | n)) * 2 + o];
    float* dst = out + ((((size_t)(b * CIN + o)) << 10) + n) * TT;
    #pragma unroll
    for (int k = 0; k < TT; k += 4)
        *(float4*)&dst[k] = make_float4(f[k], f[k + 1], f[k + 2], f[k + 3]);
}

// phase 1 of the step: agg on Abfg (576 blocks)
__global__ __launch_bounds__(256) void agg2_k(const unsigned short* __restrict__ S,
                                              const unsigned short* __restrict__ Abf,
                                              unsigned short* __restrict__ Z2) {
    __shared__ __align__(16) unsigned short lA[3][4096];
    __shared__ __align__(16) unsigned short lB[3][4096];
    agg_body(blockIdx.y * 9 + blockIdx.x, S, Abf, Z2, lA, lB);
}

// phase 1 + folded states-transpose (steps 8/16/24): blocks 0..575 agg;
// blocks 576..831 write out the previous 8-step hseq8 window (free overlap —
// both depend only on apply(t-1)).
__global__ __launch_bounds__(256) void agg2s_k(const unsigned short* __restrict__ S,
                                               const unsigned short* __restrict__ Abf,
                                               unsigned short* __restrict__ Z2,
                                               const unsigned short* __restrict__ hseq8,
                                               float* __restrict__ outS, int t0) {
    __shared__ __align__(16) unsigned short lA[3][4096];
    __shared__ __align__(16) unsigned short lB[3][4096];
    if (blockIdx.x < 576) {
        agg_body(blockIdx.x, S, Abf, Z2, lA, lB);
    } else {
        unsigned short* lt = (unsigned short*)lA;   // 9216B needed, 24KB avail
        #pragma unroll
        for (int i = 0; i < 4; i++)
            strans_body((blockIdx.x - 576) * 4 + i, hseq8, outS, t0, lt);
    }
}

// phase 2: r-gate only (u moved to phase 3). grid (256).
__global__ __launch_bounds__(256) void gates_r_k(const unsigned short* __restrict__ Z2g,
                                                 const unsigned short* __restrict__ Wb,
                                                 const float* __restrict__ br,
                                                 const float* __restrict__ h,
                                                 unsigned short* __restrict__ Z2c,
                                                 unsigned short* __restrict__ Abfc) {
    __shared__ __align__(16) unsigned short lA[3][4096];
    __shared__ __align__(16) unsigned short lB[3][4096];
    gate_body(blockIdx.x * 32, 0, Z2g, Wb, br, (const float*)0, h, (float*)0,
              Z2c, Abfc, lA, lB);
}

// phase 3: agg on Abfc (blocks 0..575) + u-gate (blocks 576..831); u depends
// only on Z2g (complete since phase 1) so it overlaps the agg tail for free.
__global__ __launch_bounds__(256) void aggu_k(const unsigned short* __restrict__ S,
                                              const unsigned short* __restrict__ Abfc,
                                              unsigned short* __restrict__ Z2c,
                                              const unsigned short* __restrict__ Z2g,
                                              const unsigned short* __restrict__ Wb,
                                              const float* __restrict__ bu,
                                              float* __restrict__ u) {
    __shared__ __align__(16) unsigned short lA[3][4096];
    __shared__ __align__(16) unsigned short lB[3][4096];
    if (blockIdx.x < 576)
        agg_body(blockIdx.x, S, Abfc, Z2c, lA, lB);
    else
        gate_body((blockIdx.x - 576) * 32, 1, Z2g, Wb, (const float*)0, bu,
                  (const float*)0, u, (unsigned short*)0, (unsigned short*)0, lA, lB);
}

// cand: cv = tanh(Wc·Z2c + bc); hraw = u*h + (1-u)*cv; per-block GN partial sums.
// BM=32 -> grid (256). NT=6, P=3.
__global__ __launch_bounds__(256) void cand_k2(const unsigned short* __restrict__ Z2c,
                                               const unsigned short* __restrict__ Wcb,
                                               const float* __restrict__ bcv,
                                               const float* __restrict__ u,
                                               const float* __restrict__ h,
                                               float* __restrict__ hraw,
                                               float* __restrict__ stats2, int t) {
    __shared__ __align__(16) unsigned short lA[3][32 * 64];
    __shared__ __align__(16) unsigned short lB[3][64 * 64];
    int tid = threadIdx.x;
    int m0 = blockIdx.x * 32;
    int lane = tid & 63, wave = tid >> 6;
    int wm = wave >> 1, wn = wave & 1;          // wave tile 16m x 32o
    float4v acc[2];
    acc[0] = (float4v){0.f, 0.f, 0.f, 0.f};
    acc[1] = (float4v){0.f, 0.f, 0.f, 0.f};
    int lrow = lane & 15, hi = lane >> 4;

    auto stage = [&](unsigned short* bufA, unsigned short* bufB, int k0) {
        {
            int cid = wave * 64 + lane;
            int r = cid >> 3, sz = cid & 7;
            GLD16(Z2c + (size_t)(m0 + r) * K2 + k0 + ((sz ^ (r & 7)) << 3),
                  bufA + wave * 512);
        }
        #pragma unroll
        for (int i = 0; i < 2; i++) {
            int cid = (i * 4 + wave) * 64 + lane;
            int r = cid >> 3, sz = cid & 7;
            GLD16(Wcb + (size_t)r * K2 + k0 + ((sz ^ (r & 7)) << 3),
                  bufB + (i * 4 + wave) * 512);
        }
    };

    unsigned short *a0 = lA[0], *a1 = lA[1], *a2 = lA[2];
    unsigned short *b0 = lB[0], *b1 = lB[1], *b2 = lB[2];
    stage(a0, b0, 0);
    stage(a1, b1, 64);
    for (int kt = 0; kt < 6; kt++) {
        if (kt < 5) asm volatile("s_waitcnt vmcnt(3)" ::: "memory");
        else        asm volatile("s_waitcnt vmcnt(0)" ::: "memory");
        __builtin_amdgcn_s_barrier();
        asm volatile("" ::: "memory");
        if (kt < 4) stage(a2, b2, (kt + 2) * 64);
        #pragma unroll
        for (int kk = 0; kk < 2; kk++) {
            int cb = kk * 4 + hi;
            short8v af, bf[2];
            {
                int lr = wm * 16 + lrow;
                af = *(const short8v*)(a0 + lr * 64 + ((cb ^ (lr & 7)) << 3));
            }
            #pragma unroll
            for (int j = 0; j < 2; j++) {
                int lr = wn * 32 + j * 16 + lrow;
                bf[j] = *(const short8v*)(b0 + lr * 64 + ((cb ^ (lr & 7)) << 3));
            }
            #pragma unroll
            for (int j = 0; j < 2; j++)
                acc[j] = __builtin_amdgcn_mfma_f32_16x16x32_bf16(af, bf[j], acc[j], 0, 0, 0);
        }
        { unsigned short* t_ = a0; a0 = a1; a1 = a2; a2 = t_; }
        { unsigned short* t_ = b0; b0 = b1; b1 = b2; b2 = t_; }
    }
    int col = lane & 15, q4 = (lane >> 4) * 4;
    float ls = 0.f, ls2 = 0.f;
    #pragma unroll
    for (int j = 0; j < 2; j++) {
        int oo = wn * 32 + j * 16 + col;
        float bias = bcv[oo];
        #pragma unroll
        for (int r = 0; r < 4; r++) {
            int m = m0 + wm * 16 + q4 + r;
            float cv = tanhf(acc[j][r] + bias);
            float uv = u[(size_t)m * HID + oo];
            float hv = h[(size_t)m * HID + oo];
            float hr = uv * hv + (1.f - uv) * cv;
            hraw[(size_t)m * HID + oo] = hr;
            ls += hr;
            ls2 = fmaf(hr, hr, ls2);
        }
    }
    ls = wave_reduce_sum(ls);
    ls2 = wave_reduce_sum(ls2);
    __shared__ float sred[8];
    if (lane == 0) { sred[wave] = ls; sred[4 + wave] = ls2; }
    __syncthreads();
    if (tid == 0) {
        float S = sred[0] + sred[1] + sred[2] + sred[3];
        float S2 = sred[4] + sred[5] + sred[6] + sred[7];
        int b = blockIdx.x >> 5, slot = blockIdx.x & 31;
        float* dst = stats2 + (((size_t)t * BB + b) * 32 + slot) * 2;
        dst[0] = S;
        dst[1] = S2;
    }
}

// apply: GN + h update + x_hat + next-step build. 8 threads per m. grid (256).
__global__ __launch_bounds__(256) void apply_k2(const float* __restrict__ hraw,
                                                const float* __restrict__ stats2,
                                                const float* __restrict__ gamma,
                                                const float* __restrict__ beta,
                                                const float* __restrict__ Wo,
                                                const float* __restrict__ bo,
                                                const float* __restrict__ x,
                                                float* __restrict__ h,
                                                unsigned short* __restrict__ Z2g,
                                                unsigned short* __restrict__ Z2c,
                                                unsigned short* __restrict__ Abfg,
                                                unsigned short* __restrict__ Abfc,
                                                unsigned short* __restrict__ hseq8,
                                                float* __restrict__ iseq, int t) {
    int gid = blockIdx.x * 256 + threadIdx.x;   // 65536
    int m = gid >> 3, q = gid & 7;
    int b = m >> 10, n = m & 1023;
    const float* st = stats2 + ((size_t)t * BB + b) * 64;
    float S = 0.f, S2 = 0.f;
    #pragma unroll
    for (int i = 0; i < 16; i++) {
        float4 p4 = *(const float4*)&st[i * 4];
        S += p4.x + p4.z;
        S2 += p4.y + p4.w;
    }
    float mean = S * (1.f / 65536.f);
    float rstd = rsqrtf(S2 * (1.f / 65536.f) - mean * mean + GN_EPS);
    bool more = (t < TT - 1);
    int c0 = q * 8;
    float v[8];
    unsigned short hb[8];
    #pragma unroll
    for (int k = 0; k < 8; k += 4) {
        float4 r4 = *(const float4*)&hraw[(size_t)m * HID + c0 + k];
        v[k + 0] = (r4.x - mean) * rstd * gamma[c0 + k + 0] + beta[c0 + k + 0];
        v[k + 1] = (r4.y - mean) * rstd * gamma[c0 + k + 1] + beta[c0 + k + 1];
        v[k + 2] = (r4.z - mean) * rstd * gamma[c0 + k + 2] + beta[c0 + k + 2];
        v[k + 3] = (r4.w - mean) * rstd * gamma[c0 + k + 3] + beta[c0 + k + 3];
    }
    float acc0 = 0.f, acc1 = 0.f;
    #pragma unroll
    for (int k = 0; k < 8; k++) {
        acc0 = fmaf(Wo[c0 + k], v[k], acc0);
        acc1 = fmaf(Wo[HID + c0 + k], v[k], acc1);
        hb[k] = f2b(v[k]);
    }
    short8v h8;
    #pragma unroll
    for (int k = 0; k < 8; k++) h8[k] = (short)hb[k];
    size_t hsbase = ((size_t)(t & 7) * 8192 + m) * HID + c0;
    *(short8v*)&hseq8[hsbase] = h8;
    if (more) {
        #pragma unroll
        for (int k = 0; k < 8; k += 4)
            *(float4*)&h[(size_t)m * HID + c0 + k] = make_float4(v[k], v[k + 1], v[k + 2], v[k + 3]);
        *(short8v*)&Z2g[(size_t)m * K2 + c0] = h8;
        #pragma unroll
        for (int k = 0; k < 8; k++)
            Abfg[(((size_t)(b * CG + c0 + k)) << 10) | n] = hb[k];
    }
    acc0 += __shfl_xor(acc0, 1, 64); acc0 += __shfl_xor(acc0, 2, 64); acc0 += __shfl_xor(acc0, 4, 64);
    acc1 += __shfl_xor(acc1, 1, 64); acc1 += __shfl_xor(acc1, 2, 64); acc1 += __shfl_xor(acc1, 4, 64);
    if (q == 0) {
        iseq[((size_t)t * 8192 + m) * 2 + 0] = acc0 + bo[0];
        iseq[((size_t)t * 8192 + m) * 2 + 1] = acc1 + bo[1];
        if (more) {
            #pragma unroll
            for (int o = 0; o < CIN; o++) {
                float xv = x[((((size_t)(b * CIN + o)) << 10) + n) * TT + t + 1];
                unsigned short xb = f2b(xv);
                Z2g[(size_t)m * K2 + HID + o] = xb;
                Z2c[(size_t)m * K2 + HID + o] = xb;
                Abfg[(((size_t)(b * CG + HID + o)) << 10) | n] = xb;
                Abfc[(((size_t)(b * CG + HID + o)) << 10) | n] = xb;
            }
        }
    }
}

// finish: blocks 0..255 write the last hseq8 window (t0=24); blocks 256..319
// do the imputation transpose (independent -> overlap).
__global__ __launch_bounds__(256) void finish_k(const unsigned short* __restrict__ hseq8,
                                                float* __restrict__ outS,
                                                const float* __restrict__ iseq,
                                                float* __restrict__ out) {
    __shared__ unsigned short lt[8 * 576];
    if (blockIdx.x < 256) {
        #pragma unroll
        for (int i = 0; i < 4; i++)
            strans_body(blockIdx.x * 4 + i, hseq8, outS, 24, lt);
    } else {
        itrans_body(blockIdx.x - 256, iseq, out);
    }
}

// ---------------- launch ----------------

extern "C" void kernel_launch(void* const* d_in, const int* in_sizes, int n_in,
                              void* d_out, int out_size, void* d_ws, size_t ws_size,
                              hipStream_t stream) {
    const float* x     = (const float*)d_in[0];
    const float* adj   = (const float*)d_in[1];
    const float* h0    = (const float*)d_in[2];
    const float* Wr    = (const float*)d_in[3];
    const float* br    = (const float*)d_in[4];
    const float* Wu    = (const float*)d_in[5];
    const float* bu    = (const float*)d_in[6];
    const float* Wc    = (const float*)d_in[7];
    const float* bcv   = (const float*)d_in[8];
    const float* gamma = (const float*)d_in[9];
    const float* beta  = (const float*)d_in[10];
    const float* Wo    = (const float*)d_in[11];
    const float* bo    = (const float*)d_in[12];
    float* out = (float*)d_out;

    char* p = (char*)d_ws;
    unsigned short* suppb = (unsigned short*)p;  p += (size_t)4 * NN * NN * 2;          // 8 MB
    unsigned short* Abfg  = (unsigned short*)p;  p += (size_t)576 * NN * 2;
    unsigned short* Abfc  = (unsigned short*)p;  p += (size_t)576 * NN * 2;
    unsigned short* Z2g   = (unsigned short*)p;  p += (size_t)8192 * K2 * 2;
    unsigned short* Z2c   = (unsigned short*)p;  p += (size_t)8192 * K2 * 2;            // adjacent to Z2g
    unsigned short* Wb    = (unsigned short*)p;  p += (size_t)128 * K2 * 2;
    unsigned short* Wcb   = (unsigned short*)p;  p += (size_t)64 * K2 * 2;
    float* u     = (float*)p;  p += (size_t)8192 * HID * 4;
    float* h     = (float*)p;  p += (size_t)8192 * HID * 4;
    float* hraw  = (float*)p;  p += (size_t)8192 * HID * 4;
    unsigned short* hseq8 = (unsigned short*)p;  p += (size_t)8 * 8192 * HID * 2;       // 8 MB
    float* iseq  = (float*)p;  p += (size_t)TT * 8192 * 2 * 4;
    float* rowsum = (float*)p; p += NN * 4;
    float* cpart  = (float*)p; p += (size_t)8 * NN * 4;
    float* stats2 = (float*)p; p += (size_t)TT * BB * 32 * 2 * 4;

    float* outS = out + (size_t)BB * CIN * NN * TT;

    rowsum_k<<<NN, 256, 0, stream>>>(adj, rowsum);
    colsum_k<<<32, 256, 0, stream>>>(adj, cpart);
    fwdb_k<<<(NN * NN) / 256, 256, 0, stream>>>(adj, rowsum, suppb);
    bwdb_k<<<dim3(32, 32), dim3(32, 8), 0, stream>>>(adj, cpart, suppb + (size_t)NN * NN);
    suppk_mfma<<<dim3(8, 16, 2), 256, 0, stream>>>(suppb, suppb + (size_t)2 * NN * NN);
    wconv_k<<<(192 * K2) / 256, 256, 0, stream>>>(Wr, Wu, Wc, Wb, Wcb);
    zeroz_k<<<(2 * 8192 * K2) / (8 * 256), 256, 0, stream>>>(Z2g);
    init_k<<<8192 / 256, 256, 0, stream>>>(x, h0, h, Z2g, Z2c, Abfg, Abfc);

    for (int t = 0; t < TT; t++) {
        if (t > 0 && (t & 7) == 0)
            agg2s_k<<<832, 256, 0, stream>>>(suppb, Abfg, Z2g, hseq8, outS, t - 8);
        else
            agg2_k<<<dim3(9, 64), 256, 0, stream>>>(suppb, Abfg, Z2g);
        gates_r_k<<<256, 256, 0, stream>>>(Z2g, Wb, br, h, Z2c, Abfc);
        aggu_k<<<832, 256, 0, stream>>>(suppb, Abfc, Z2c, Z2g, Wb, bu, u);
        cand_k2<<<256, 256, 0, stream>>>(Z2c, Wcb, bcv, u, h, hraw, stats2, t);
        apply_k2<<<256, 256, 0, stream>>>(hraw, stats2, gamma, beta, Wo, bo, x, h,
                                          Z2g, Z2c, Abfg, Abfc, hseq8, iseq, t);
    }
    finish_k<<<320, 256, 0, stream>>>(hseq8, outS, iseq, out);
}